// Round 11
// baseline (10981.428 us; speedup 1.0000x reference)
//
#include <hip/hip_runtime.h>
#include <hip/hip_fp16.h>

typedef _Float16 f16;
typedef _Float16 half8 __attribute__((ext_vector_type(8)));
typedef _Float16 half4v __attribute__((ext_vector_type(4)));
typedef float floatx4 __attribute__((ext_vector_type(4)));
typedef unsigned long long u64;

#define SEQ   256
#define BATCH 128
#define HID   512
#define NL    2
#define TAPE  30
#define NG    2048   // 4*HID
#define NBLK  256

__device__ __forceinline__ float fsig(float x)  { return 1.f/(1.f+__expf(-x)); }
__device__ __forceinline__ float ftanh(float x) { return 1.f - 2.f/(1.f+__expf(2.f*x)); }

__device__ __forceinline__ unsigned packh2(float a, float b){
    union { f16 h[2]; unsigned u; } c; c.h[0]=(f16)a; c.h[1]=(f16)b; return c.u;
}
__device__ __forceinline__ float2 unpackh2(unsigned u){
    union { unsigned u; f16 h[2]; } c; c.u=u;
    float2 r; r.x=(float)c.h[0]; r.y=(float)c.h[1]; return r;
}

// ---- TREE grid barrier with writeback/invalidate protocol ----
// R10 discovery: sc1 (agent) data stores stream through to HBM (no-allocate);
// consumers then re-fetch from HBM -> ~4MB/phase of HBM round trips = the
// 15.7us/phase floor (hbm_bytes/266GB/s == dur exactly).
// New protocol: producers use NORMAL stores (dirty in local L2). At barrier
// entry thread0 issues fence(RELEASE, agent) -> s_waitcnt + buffer_wbl2:
// writes the XCD's dirty L2 lines back to L3 (allocating). After the release
// is observed, fence(ACQUIRE, agent) -> buffer_inv: subsequent cached loads
// refill from L3. HBM is out of the loop. Barrier words stay sc1 (tiny).
// Tree arrival: 16 leaves (128B apart) x 16 blocks -> root -> release word.
// Counters are monotonic; (count & 15)==15 marks the last arrival.
#define BAR_ROOT 512
#define BAR_REL  544
__device__ __forceinline__ void gridbar(unsigned* bar, unsigned gen){
    __syncthreads();                  // compiler drains vmcnt before s_barrier
    if (threadIdx.x == 0){
        __builtin_amdgcn_fence(__ATOMIC_RELEASE, "agent");   // buffer_wbl2 -> L3
        unsigned* leaf = bar + ((blockIdx.x >> 4) << 5);     // 16 blocks/leaf
        bool releaser = false;
        unsigned p = __hip_atomic_fetch_add(leaf, 1u, __ATOMIC_RELAXED, __HIP_MEMORY_SCOPE_AGENT);
        if ((p & 15u) == 15u){
            unsigned q = __hip_atomic_fetch_add(bar + BAR_ROOT, 1u, __ATOMIC_RELAXED, __HIP_MEMORY_SCOPE_AGENT);
            if ((q & 15u) == 15u){
                __hip_atomic_store(bar + BAR_REL, gen, __ATOMIC_RELAXED, __HIP_MEMORY_SCOPE_AGENT);
                releaser = true;
            }
        }
        if (!releaser){
            while (__hip_atomic_load(bar + BAR_REL, __ATOMIC_RELAXED, __HIP_MEMORY_SCOPE_AGENT) < gen){
                __builtin_amdgcn_s_sleep(8);
            }
        }
        __builtin_amdgcn_fence(__ATOMIC_ACQUIRE, "agent");   // buffer_inv
    }
    __syncthreads();
}

// ---------------- setup: gate-permuted fp16 weights ----------------
__global__ void k_setup_w(const float* __restrict__ W_ih, const float* __restrict__ W_hh,
                          const float* __restrict__ b_ih, const float* __restrict__ b_hh,
                          f16* __restrict__ Wcat, float* __restrict__ bsum)
{
    int idx = blockIdx.x*256 + threadIdx.x;      // 2*2048*1024 threads
    int l = idx >> 21;
    int r = (idx >> 10) & 2047;
    int k = idx & 1023;
    int gate = r & 3, h = r >> 2;
    int orig = gate*HID + h;
    float wv = (k < 512) ? W_ih[((size_t)l*NG + orig)*512 + k]
                         : W_hh[((size_t)l*NG + orig)*512 + (k-512)];
    Wcat[idx] = (f16)wv;
    if (idx < NL*NG) {
        int l2 = idx >> 11, r2 = idx & 2047;
        int g2 = r2 & 3, h2 = r2 >> 2;
        int o2 = g2*HID + h2;
        bsum[idx] = b_ih[l2*NG + o2] + b_hh[l2*NG + o2];
    }
}

__global__ void k_setup_misc(const float* __restrict__ attn_wx, const float* __restrict__ attn_wh,
                             const float* __restrict__ attn_wht, const float* __restrict__ attn_v,
                             f16* __restrict__ awx, float* __restrict__ whd,
                             float* __restrict__ whtd, float* __restrict__ av)
{
    int idx = blockIdx.x*256 + threadIdx.x;      // 2*512*512 threads
    awx[idx] = (f16)attn_wx[idx];
    if (idx < NL*HID) {
        int l = idx >> 9, h = idx & 511;
        whd[idx]  = attn_wh[((size_t)l*HID + h)*HID + h];
        whtd[idx] = attn_wht[((size_t)l*HID + h)*HID + h];
        av[idx]   = attn_v[idx];
    }
}

__global__ void k_xs16(const float* __restrict__ x, f16* __restrict__ o)
{
    size_t i = ((size_t)blockIdx.x*256 + threadIdx.x)*4;
    float4 v = *(const float4*)(x + i);
    half4v h; h[0]=(f16)v.x; h[1]=(f16)v.y; h[2]=(f16)v.z; h[3]=(f16)v.w;
    *(half4v*)(o + i) = h;
}

#define MFMA4(af, bf) do { \
    acc[0][0] = __builtin_amdgcn_mfma_f32_16x16x32_f16(af[0], bf[0], acc[0][0], 0, 0, 0); \
    acc[0][1] = __builtin_amdgcn_mfma_f32_16x16x32_f16(af[0], bf[1], acc[0][1], 0, 0, 0); \
    acc[1][0] = __builtin_amdgcn_mfma_f32_16x16x32_f16(af[1], bf[0], acc[1][0], 0, 0, 0); \
    acc[1][1] = __builtin_amdgcn_mfma_f32_16x16x32_f16(af[1], bf[1], acc[1][1], 0, 0, 0); \
} while(0)

// ---------------- x_attn precompute ----------------
__global__ __launch_bounds__(512) void k_xattn(const f16* __restrict__ Xf,
                                               const f16* __restrict__ AWX,
                                               f16* __restrict__ XA)
{
    int nb = blockIdx.x;            // 0..7
    int t  = blockIdx.y;            // 0..255
    int l  = blockIdx.z;            // 0..1
    const f16* A  = Xf  + (size_t)t*(BATCH*512);
    const f16* Bm = AWX + (size_t)l*(512*512);
    int lane = threadIdx.x & 63, wid = threadIdx.x >> 6;
    int wm = wid >> 1, wn = wid & 1;
    int row0 = wm*32 + (lane & 15);
    int col0 = nb*64 + wn*32 + (lane & 15);
    int kc = (lane >> 4)*8;
    const f16* a_base = A  + row0*512 + kc;
    const f16* b_base = Bm + col0*512 + kc;
    floatx4 acc[2][2] = {};
    #pragma unroll 4
    for (int ks = 0; ks < 16; ks++){
        half8 af[2], bf[2];
        af[0] = *(const half8*)(a_base + ks*32);
        af[1] = *(const half8*)(a_base + 8192 + ks*32);
        bf[0] = *(const half8*)(b_base + ks*32);
        bf[1] = *(const half8*)(b_base + 8192 + ks*32);
        MFMA4(af, bf);
    }
    int rr = (lane >> 4)*4;
    #pragma unroll
    for (int mi = 0; mi < 2; mi++)
    #pragma unroll
    for (int ni = 0; ni < 2; ni++)
    #pragma unroll
    for (int j = 0; j < 4; j++){
        int brow = wm*32 + mi*16 + rr + j;
        int ch   = nb*64 + wn*32 + ni*16 + (lane & 15);
        XA[(((size_t)t*NL + l)*BATCH + brow)*HID + ch] = (f16)acc[mi][ni][j];
    }
}

// ---------------- tape fill (zero initial state, K=512) ----------------
__global__ __launch_bounds__(512) void k_fill(const f16* __restrict__ A0all,
                                              const f16* __restrict__ B,
                                              const float* __restrict__ bsum_l,
                                              f16* __restrict__ htape16, float* __restrict__ ctape,
                                              int l, f16* __restrict__ h0out)
{
    int y  = blockIdx.y;                         // step 0..29 (== slot)
    int nb = blockIdx.x;                         // 0..31
    const f16* A0 = A0all + (size_t)y*(BATCH*HID);
    if (h0out) h0out += (size_t)y*(BATCH*HID);

    int tid = threadIdx.x, lane = tid & 63, wid = tid >> 6;
    int wm = wid >> 1, wn = wid & 1;
    int row0 = wm*32 + (lane & 15);
    int col0 = nb*64 + wn*32 + (lane & 15);
    int kc = (lane >> 4)*8;
    const f16* a_base = A0 + row0*512 + kc;
    const f16* b_base = B + (size_t)col0*1024 + kc;

    floatx4 acc[2][2] = {};
    #pragma unroll
    for (int ks = 0; ks < 16; ks++){
        half8 af[2], bf[2];
        af[0] = *(const half8*)(a_base + ks*32);
        af[1] = *(const half8*)(a_base + 16*512 + ks*32);
        bf[0] = *(const half8*)(b_base + ks*32);
        bf[1] = *(const half8*)(b_base + (size_t)16*1024 + ks*32);
        MFMA4(af, bf);
    }

    __shared__ float Cl[128][65];
    int rr = (lane >> 4)*4;
    #pragma unroll
    for (int mi = 0; mi < 2; mi++)
    #pragma unroll
    for (int ni = 0; ni < 2; ni++){
        float bias = bsum_l[col0 + ni*16];
        #pragma unroll
        for (int j = 0; j < 4; j++)
            Cl[wm*32 + mi*16 + rr + j][wn*32 + ni*16 + (lane & 15)] = acc[mi][ni][j] + bias;
    }
    __syncthreads();

    #pragma unroll
    for (int it = 0; it < 4; it++){
        int item = tid + it*512;
        int b = item >> 4, hl = item & 15;
        float gi = Cl[b][hl*4+0];
        float gg = Cl[b][hl*4+2];
        float go = Cl[b][hl*4+3];
        int hg = nb*16 + hl;
        float cn = fsig(gi)*ftanh(gg);           // cprev == 0
        float hn = fsig(go)*ftanh(cn);
        size_t toff = (((size_t)y*NL + l)*BATCH + b)*HID + hg;
        htape16[toff] = (f16)hn;
        ctape[toff]   = cn;
        if (h0out) h0out[b*HID + hg] = (f16)hn;
    }
}

// ---------------- persistent scan kernel (plain launch, custom barrier) ----------------
// 256 blocks x 98.8 KiB LDS => exactly 1 block/CU, grid == #CUs => all blocks
// co-resident by construction; no cooperative launch needed.
struct SArgs {
    const f16* xsf; const f16* xattn; const f16* Wcat; const float* bsum;
    const float* whd; const float* whtd; const float* av;
    const f16* htape16; const float* ctape;   // ring init (k_fill output)
    float* prevc; f16* prevh16;
    f16* h016; float2* slotstage; float* out;
    unsigned* bar;
};

__global__ __launch_bounds__(256, 1) void k_scan(SArgs A)
{
    __shared__ f16 Wsh[16*1024];          // 32 KiB: this block's 16 gate-cols, XOR-swizzled
    __shared__ float2 stg[128*4];         // 4 KiB epilogue staging {h,c}
    __shared__ float wpart[TAPE][4];
    __shared__ unsigned ringH[TAPE][256]; // 30 KiB: tape h, packed f16x2 per thread
    __shared__ unsigned ringC[TAPE][256]; // 30 KiB: tape c, packed f16x2 per thread

    const int blk = blockIdx.x;
    const int tid = threadIdx.x;
    const int lane = tid & 63, wv = tid >> 6;
    const int myl = blk >> 7;           // 0: blocks 0..127 (gemm_l0 + attn_l0), 1: 128..255
    const int cb  = blk & 127;          // gemm: 16 gate-cols -> 4 h
    const int b   = blk & 127;          // attn: batch index
    const int h0  = tid*2;              // attn: h pair
    const size_t BH = (size_t)BATCH*HID;

    // ---- weights to LDS (once) ----
    {
        const f16* src = A.Wcat + ((size_t)myl*NG + (size_t)cb*16)*1024;
        for (int i = tid; i < 2048; i += 256){
            int c = i >> 7;              // 0..15
            int k = (i & 127)*8;
            int dst = (c << 10) | (k ^ ((c & 7) << 3));
            *(half8*)&Wsh[dst] = *(const half8*)(src + ((size_t)c << 10) + k);
        }
    }

    // ---- tape ring -> LDS (packed f16x2 per thread) ----
    float phx = 0.f, phy = 0.f;          // prev_h (this block's layer), lives in regs
    #pragma unroll
    for (int p = 0; p < TAPE; p++){
        size_t off = (((size_t)p*NL + myl)*BATCH + b)*HID + h0;
        ringH[p][tid] = *(const unsigned*)(A.htape16 + off);
        float2 cc = *(const float2*)(A.ctape + off);
        ringC[p][tid] = packh2(cc.x, cc.y);
    }
    __syncthreads();

    // ---- attention for this block's (myl, b) ----
    auto do_attn = [&](int t, bool consume){
        if (consume){
            int snew = (t-1) % TAPE;
            // cached float4 load; fresh after gridbar's acquire fence
            float4 v = *(const float4*)(A.slotstage + ((size_t)myl*BATCH + b)*HID + h0);
            ringH[snew][tid] = packh2(v.x, v.z);   // {h(h0), h(h0+1)}
            ringC[snew][tid] = packh2(v.y, v.w);   // {c(h0), c(h0+1)}
        }
        size_t pb = ((size_t)myl*BATCH + b)*HID + h0;
        unsigned xu = *(const unsigned*)(A.xattn + (((size_t)t*NL + myl)*BATCH + b)*HID + h0);
        float2 xa = unpackh2(xu);
        int hw = myl*HID + h0;
        float wdx = A.whd[hw],  wdy = A.whd[hw+1];
        float wtx = A.whtd[hw], wty = A.whtd[hw+1];
        float vvx = A.av[hw],   vvy = A.av[hw+1];
        float bx = xa.x + phx*wtx, by = xa.y + phy*wty;

        float sc[TAPE];
        #pragma unroll
        for (int p = 0; p < TAPE; p++){
            float2 hv = unpackh2(ringH[p][tid]);
            float ax = ftanh(hv.x*wdx + bx);
            float ay = ftanh(hv.y*wdy + by);
            float s = ax*vvx + ay*vvy;
            #pragma unroll
            for (int o = 32; o; o >>= 1) s += __shfl_xor(s, o);
            if (lane == 0) wpart[p][wv] = s;
        }
        __syncthreads();
        float m = -1e30f;
        #pragma unroll
        for (int p = 0; p < TAPE; p++){
            sc[p] = wpart[p][0] + wpart[p][1] + wpart[p][2] + wpart[p][3];
            m = fmaxf(m, sc[p]);
        }
        float Z = 0.f;
        #pragma unroll
        for (int p = 0; p < TAPE; p++){ sc[p] = __expf(sc[p] - m); Z += sc[p]; }
        float inv = 1.f/Z;
        float ahx=0.f, ahy=0.f, acx=0.f, acy=0.f;
        #pragma unroll
        for (int p = 0; p < TAPE; p++){
            float2 hv = unpackh2(ringH[p][tid]);
            float2 cv = unpackh2(ringC[p][tid]);
            ahx += sc[p]*hv.x; ahy += sc[p]*hv.y;
            acx += sc[p]*cv.x; acy += sc[p]*cv.y;
        }
        ahx*=inv; ahy*=inv; acx*=inv; acy*=inv;
        phx = ahx; phy = ahy;
        // NORMAL stores; flushed to L3 by the release fence in gridbar
        *(unsigned*)(A.prevh16 + pb) = packh2(ahx, ahy);
        float2 pcf; pcf.x = acx; pcf.y = acy;
        *(float2*)(A.prevc + pb) = pcf;
    };

    // ---- gemm for this block's layer: 128 rows x 16 gate-cols, K=1024 ----
    // All A/cprev reads are NORMAL cached loads: 16 blocks per XCD share one
    // L2 fill of the panels; data comes from L3 (wbl2'd there), never HBM.
    auto do_gemm = [&](const f16* A0base, const f16* A1base,
                       f16* h0out, float* outp){
        int rowT = wv*32;
        int row0 = rowT + (lane & 15);
        int kc = (lane >> 4)*8;
        const f16* a0 = A0base + (size_t)row0*512 + kc;
        const f16* a1 = A1base + (size_t)row0*512 + kc;
        int colL = lane & 15;
        int bofs = colL << 10;
        int sw = (colL & 7) << 3;
        int rr = (lane >> 4) << 2;
        int hL = colL >> 2;
        int hG = cb*4 + hL;

        // early cprev loads (cached), consumed in the epilogue
        const float* cprev_l = A.prevc + (size_t)myl*BH;
        float cp[2][4];
        #pragma unroll
        for (int mi = 0; mi < 2; mi++)
        #pragma unroll
        for (int j = 0; j < 4; j++)
            cp[mi][j] = cprev_l[(size_t)(rowT + mi*16 + rr + j)*HID + hG];

        floatx4 acc0 = {0,0,0,0}, acc1 = {0,0,0,0};
        #pragma unroll
        for (int ks = 0; ks < 16; ks++){
            half8 af0 = *(const half8*)(a0 + ks*32);
            half8 af1 = *(const half8*)(a0 + ks*32 + 16*512);
            int kx = (kc + ks*32) ^ sw;
            half8 bf = *(const half8*)&Wsh[bofs + kx];
            acc0 = __builtin_amdgcn_mfma_f32_16x16x32_f16(af0, bf, acc0, 0, 0, 0);
            acc1 = __builtin_amdgcn_mfma_f32_16x16x32_f16(af1, bf, acc1, 0, 0, 0);
        }
        #pragma unroll
        for (int ks = 0; ks < 16; ks++){
            half8 af0 = *(const half8*)(a1 + ks*32);
            half8 af1 = *(const half8*)(a1 + ks*32 + 16*512);
            int kx = (kc + (ks+16)*32) ^ sw;
            half8 bf = *(const half8*)&Wsh[bofs + kx];
            acc0 = __builtin_amdgcn_mfma_f32_16x16x32_f16(af0, bf, acc0, 0, 0, 0);
            acc1 = __builtin_amdgcn_mfma_f32_16x16x32_f16(af1, bf, acc1, 0, 0, 0);
        }

        // epilogue: quad-shfl gate transpose + cell update -> LDS stage
        int baseLane = lane & 60;
        float bias = A.bsum[myl*NG + cb*16 + colL];
        #pragma unroll
        for (int mi = 0; mi < 2; mi++){
            #pragma unroll
            for (int j = 0; j < 4; j++){
                float g = (mi ? acc1[j] : acc0[j]) + bias;
                float gi = __shfl(g, baseLane+0);
                float gf = __shfl(g, baseLane+1);
                float gg = __shfl(g, baseLane+2);
                float go = __shfl(g, baseLane+3);
                int row = rowT + mi*16 + rr + j;
                float cn = fsig(gf)*cp[mi][j] + fsig(gi)*ftanh(gg);
                float hn = fsig(go)*ftanh(cn);
                if ((lane & 3) == 0){ float2 v; v.x=hn; v.y=cn; stg[row*4 + hL] = v; }
            }
        }
        __syncthreads();
        // publish new tape slot {h,c} via NORMAL wide stores (wbl2 -> L3 at barrier)
        float2* slot2 = A.slotstage + (size_t)myl*BH;
        {
            int row = tid >> 1, half = tid & 1;        // 128 rows x 2 halves, 16B each
            float4 v = *(const float4*)&stg[row*4 + half*2];
            *(float4*)&slot2[(size_t)row*HID + cb*4 + half*2] = v;
        }
        if (tid < 128){
            int row = tid;
            if (myl == 0){
                union { f16 h[4]; u64 u; } pk;
                pk.h[0]=(f16)stg[row*4+0].x; pk.h[1]=(f16)stg[row*4+1].x;
                pk.h[2]=(f16)stg[row*4+2].x; pk.h[3]=(f16)stg[row*4+3].x;
                *(u64*)(h0out + (size_t)row*512 + cb*4) = pk.u;
            } else {
                float4 v; v.x=stg[row*4+0].x; v.y=stg[row*4+1].x;
                          v.z=stg[row*4+2].x; v.w=stg[row*4+3].x;
                *(float4*)(outp + (size_t)row*512 + cb*4) = v;
            }
        }
    };

    // ---- prologue: attn_l0(TAPE) on lower half ----
    if (myl == 0) do_attn(TAPE, false);
    unsigned gen = 0;
    gridbar(A.bar, ++gen);

    // ---- main scan: 2 barriers / step, every block busy every phase ----
    for (int t = TAPE; t < SEQ; ++t){
        // Phase A: gemm_l0(t) [blocks 0..127]  ||  attn_l1(t) [blocks 128..255]
        if (myl == 0) do_gemm(A.xsf + (size_t)t*BH, A.prevh16, A.h016, nullptr);
        else          do_attn(t, t > TAPE);
        gridbar(A.bar, ++gen);
        // Phase B: gemm_l1(t) [blocks 128..255]  ||  attn_l0(t+1) [blocks 0..127]
        if (myl == 1) do_gemm(A.h016, A.prevh16 + BH, nullptr,
                              A.out + (size_t)((t-16) % TAPE)*BH);
        else if (t + 1 < SEQ) do_attn(t + 1, true);
        gridbar(A.bar, ++gen);
    }
}

// ---------------- host ----------------
extern "C" void kernel_launch(void* const* d_in, const int* in_sizes, int n_in,
                              void* d_out, int out_size, void* d_ws, size_t ws_size,
                              hipStream_t stream)
{
    (void)in_sizes; (void)n_in; (void)out_size; (void)ws_size;
    const float* xs       = (const float*)d_in[0];
    const float* W_ih     = (const float*)d_in[1];
    const float* W_hh     = (const float*)d_in[2];
    const float* b_ih     = (const float*)d_in[3];
    const float* b_hh     = (const float*)d_in[4];
    const float* attn_wh  = (const float*)d_in[5];
    const float* attn_wx  = (const float*)d_in[6];
    const float* attn_wht = (const float*)d_in[7];
    const float* attn_v   = (const float*)d_in[8];
    float* out = (float*)d_out;

    char* w = (char*)d_ws;
    auto alloc = [&](size_t bytes)->char*{ char* p = w; w += (bytes + 255) & ~(size_t)255; return p; };
    f16*   Wcat    = (f16*)   alloc((size_t)NL*NG*1024*2);
    float* bsum    = (float*) alloc((size_t)NL*NG*4);
    f16*   awx     = (f16*)   alloc((size_t)NL*HID*HID*2);
    float* whd     = (float*) alloc((size_t)NL*HID*4);
    float* whtd    = (float*) alloc((size_t)NL*HID*4);
    float* av      = (float*) alloc((size_t)NL*HID*4);
    f16*   xsf     = (f16*)   alloc((size_t)SEQ*BATCH*HID*2);
    f16*   xattn   = (f16*)   alloc((size_t)SEQ*NL*BATCH*HID*2);
    f16*   htape16 = (f16*)   alloc((size_t)TAPE*NL*BATCH*HID*2);
    float* ctape   = (float*) alloc((size_t)TAPE*NL*BATCH*HID*4);
    float* prevc   = (float*) alloc((size_t)NL*BATCH*HID*4);
    f16*   prevh16 = (f16*)   alloc((size_t)NL*BATCH*HID*2);
    f16*   h016    = (f16*)   alloc((size_t)BATCH*HID*2);
    f16*   h0all   = (f16*)   alloc((size_t)TAPE*BATCH*HID*2);
    float2* slotstage = (float2*)alloc((size_t)NL*BATCH*HID*8);
    unsigned* bar  = (unsigned*)alloc(4096);   // 16 leaves (128B apart) + root + rel

    hipMemsetAsync(prevc,   0, (size_t)NL*BATCH*HID*4, stream);
    hipMemsetAsync(prevh16, 0, (size_t)NL*BATCH*HID*2, stream);
    hipMemsetAsync(bar,     0, 4096, stream);

    k_setup_w   <<<dim3(16384), dim3(256), 0, stream>>>(W_ih, W_hh, b_ih, b_hh, Wcat, bsum);
    k_setup_misc<<<dim3(2048),  dim3(256), 0, stream>>>(attn_wx, attn_wh, attn_wht, attn_v, awx, whd, whtd, av);
    k_xs16      <<<dim3(16384), dim3(256), 0, stream>>>(xs, xsf);
    k_xattn     <<<dim3(8, SEQ, NL), dim3(512), 0, stream>>>(xsf, awx, xattn);

    k_fill<<<dim3(32, TAPE), dim3(512), 0, stream>>>(xsf, Wcat, bsum, htape16, ctape, 0, h0all);
    k_fill<<<dim3(32, TAPE), dim3(512), 0, stream>>>(h0all, Wcat + (size_t)NG*1024, bsum + NG,
                                                     htape16, ctape, 1, nullptr);

    // Plain (non-cooperative) launch of the persistent scan. 256 blocks with
    // 98.8 KiB LDS each = 1 block/CU on a 256-CU chip: all blocks co-resident
    // by construction, and plain launches are graph-capture-safe.
    SArgs sa;
    sa.xsf = xsf; sa.xattn = xattn; sa.Wcat = Wcat; sa.bsum = bsum;
    sa.whd = whd; sa.whtd = whtd; sa.av = av;
    sa.htape16 = htape16; sa.ctape = ctape;
    sa.prevc = prevc; sa.prevh16 = prevh16;
    sa.h016 = h016; sa.slotstage = slotstage; sa.out = out;
    sa.bar = bar;
    k_scan<<<dim3(NBLK), dim3(256), 0, stream>>>(sa);
}

// Round 12
// 7353.997 us; speedup vs baseline: 1.4933x; 1.4933x over previous
//
#include <hip/hip_runtime.h>
#include <hip/hip_fp16.h>

typedef _Float16 f16;
typedef _Float16 half8 __attribute__((ext_vector_type(8)));
typedef _Float16 half4v __attribute__((ext_vector_type(4)));
typedef float floatx4 __attribute__((ext_vector_type(4)));
typedef unsigned long long u64;

#define SEQ   256
#define BATCH 128
#define HID   512
#define NL    2
#define TAPE  30
#define NG    2048   // 4*HID
#define NBLK  256

__device__ __forceinline__ float fsig(float x)  { return 1.f/(1.f+__expf(-x)); }
__device__ __forceinline__ float ftanh(float x) { return 1.f - 2.f/(1.f+__expf(2.f*x)); }

// ---- agent-scope relaxed atomic STORES (sc1) — R10's proven protocol ----
__device__ __forceinline__ void ast64(void* p, u64 v){
    __hip_atomic_store((u64*)p, v, __ATOMIC_RELAXED, __HIP_MEMORY_SCOPE_AGENT);
}
__device__ __forceinline__ void ast32(void* p, unsigned v){
    __hip_atomic_store((unsigned*)p, v, __ATOMIC_RELAXED, __HIP_MEMORY_SCOPE_AGENT);
}
__device__ __forceinline__ unsigned packh2(float a, float b){
    union { f16 h[2]; unsigned u; } c; c.h[0]=(f16)a; c.h[1]=(f16)b; return c.u;
}
__device__ __forceinline__ float2 unpackh2(unsigned u){
    union { unsigned u; f16 h[2]; } c; c.u=u;
    float2 r; r.x=(float)c.h[0]; r.y=(float)c.h[1]; return r;
}

// ---- TREE grid barrier (R10, best measured): sc1 arrival tree + one
// acquire fence (buffer_inv) per block on exit. NO release/wbl2 (R11 regressed).
#define BAR_ROOT 512
#define BAR_REL  544
__device__ __forceinline__ void gridbar(unsigned* bar, unsigned gen){
    __syncthreads();                  // drains vmcnt -> prior sc1 stores visible at L3
    if (threadIdx.x == 0){
        unsigned* leaf = bar + ((blockIdx.x >> 4) << 5);   // 16 blocks/leaf, 128B apart
        bool releaser = false;
        unsigned p = __hip_atomic_fetch_add(leaf, 1u, __ATOMIC_RELAXED, __HIP_MEMORY_SCOPE_AGENT);
        if ((p & 15u) == 15u){
            unsigned q = __hip_atomic_fetch_add(bar + BAR_ROOT, 1u, __ATOMIC_RELAXED, __HIP_MEMORY_SCOPE_AGENT);
            if ((q & 15u) == 15u){
                __hip_atomic_store(bar + BAR_REL, gen, __ATOMIC_RELAXED, __HIP_MEMORY_SCOPE_AGENT);
                releaser = true;
            }
        }
        if (!releaser){
            while (__hip_atomic_load(bar + BAR_REL, __ATOMIC_RELAXED, __HIP_MEMORY_SCOPE_AGENT) < gen){
                __builtin_amdgcn_s_sleep(8);
            }
        }
        __builtin_amdgcn_fence(__ATOMIC_ACQUIRE, "agent");   // one buffer_inv per block
    }
    __syncthreads();
}

// ---------------- setup: gate-permuted fp16 weights ----------------
__global__ void k_setup_w(const float* __restrict__ W_ih, const float* __restrict__ W_hh,
                          const float* __restrict__ b_ih, const float* __restrict__ b_hh,
                          f16* __restrict__ Wcat, float* __restrict__ bsum)
{
    int idx = blockIdx.x*256 + threadIdx.x;      // 2*2048*1024 threads
    int l = idx >> 21;
    int r = (idx >> 10) & 2047;
    int k = idx & 1023;
    int gate = r & 3, h = r >> 2;
    int orig = gate*HID + h;
    float wv = (k < 512) ? W_ih[((size_t)l*NG + orig)*512 + k]
                         : W_hh[((size_t)l*NG + orig)*512 + (k-512)];
    Wcat[idx] = (f16)wv;
    if (idx < NL*NG) {
        int l2 = idx >> 11, r2 = idx & 2047;
        int g2 = r2 & 3, h2 = r2 >> 2;
        int o2 = g2*HID + h2;
        bsum[idx] = b_ih[l2*NG + o2] + b_hh[l2*NG + o2];
    }
}

__global__ void k_setup_misc(const float* __restrict__ attn_wx, const float* __restrict__ attn_wh,
                             const float* __restrict__ attn_wht, const float* __restrict__ attn_v,
                             f16* __restrict__ awx, float* __restrict__ whd,
                             float* __restrict__ whtd, float* __restrict__ av)
{
    int idx = blockIdx.x*256 + threadIdx.x;      // 2*512*512 threads
    awx[idx] = (f16)attn_wx[idx];
    if (idx < NL*HID) {
        int l = idx >> 9, h = idx & 511;
        whd[idx]  = attn_wh[((size_t)l*HID + h)*HID + h];
        whtd[idx] = attn_wht[((size_t)l*HID + h)*HID + h];
        av[idx]   = attn_v[idx];
    }
}

__global__ void k_xs16(const float* __restrict__ x, f16* __restrict__ o)
{
    size_t i = ((size_t)blockIdx.x*256 + threadIdx.x)*4;
    float4 v = *(const float4*)(x + i);
    half4v h; h[0]=(f16)v.x; h[1]=(f16)v.y; h[2]=(f16)v.z; h[3]=(f16)v.w;
    *(half4v*)(o + i) = h;
}

#define MFMA4(af, bf) do { \
    acc[0][0] = __builtin_amdgcn_mfma_f32_16x16x32_f16(af[0], bf[0], acc[0][0], 0, 0, 0); \
    acc[0][1] = __builtin_amdgcn_mfma_f32_16x16x32_f16(af[0], bf[1], acc[0][1], 0, 0, 0); \
    acc[1][0] = __builtin_amdgcn_mfma_f32_16x16x32_f16(af[1], bf[0], acc[1][0], 0, 0, 0); \
    acc[1][1] = __builtin_amdgcn_mfma_f32_16x16x32_f16(af[1], bf[1], acc[1][1], 0, 0, 0); \
} while(0)

// ---------------- x_attn precompute ----------------
__global__ __launch_bounds__(512) void k_xattn(const f16* __restrict__ Xf,
                                               const f16* __restrict__ AWX,
                                               f16* __restrict__ XA)
{
    int nb = blockIdx.x;            // 0..7
    int t  = blockIdx.y;            // 0..255
    int l  = blockIdx.z;            // 0..1
    const f16* A  = Xf  + (size_t)t*(BATCH*512);
    const f16* Bm = AWX + (size_t)l*(512*512);
    int lane = threadIdx.x & 63, wid = threadIdx.x >> 6;
    int wm = wid >> 1, wn = wid & 1;
    int row0 = wm*32 + (lane & 15);
    int col0 = nb*64 + wn*32 + (lane & 15);
    int kc = (lane >> 4)*8;
    const f16* a_base = A  + row0*512 + kc;
    const f16* b_base = Bm + col0*512 + kc;
    floatx4 acc[2][2] = {};
    #pragma unroll 4
    for (int ks = 0; ks < 16; ks++){
        half8 af[2], bf[2];
        af[0] = *(const half8*)(a_base + ks*32);
        af[1] = *(const half8*)(a_base + 8192 + ks*32);
        bf[0] = *(const half8*)(b_base + ks*32);
        bf[1] = *(const half8*)(b_base + 8192 + ks*32);
        MFMA4(af, bf);
    }
    int rr = (lane >> 4)*4;
    #pragma unroll
    for (int mi = 0; mi < 2; mi++)
    #pragma unroll
    for (int ni = 0; ni < 2; ni++)
    #pragma unroll
    for (int j = 0; j < 4; j++){
        int brow = wm*32 + mi*16 + rr + j;
        int ch   = nb*64 + wn*32 + ni*16 + (lane & 15);
        XA[(((size_t)t*NL + l)*BATCH + brow)*HID + ch] = (f16)acc[mi][ni][j];
    }
}

// ---------------- tape fill (zero initial state, K=512) ----------------
__global__ __launch_bounds__(512) void k_fill(const f16* __restrict__ A0all,
                                              const f16* __restrict__ B,
                                              const float* __restrict__ bsum_l,
                                              f16* __restrict__ htape16, float* __restrict__ ctape,
                                              int l, f16* __restrict__ h0out)
{
    int y  = blockIdx.y;                         // step 0..29 (== slot)
    int nb = blockIdx.x;                         // 0..31
    const f16* A0 = A0all + (size_t)y*(BATCH*HID);
    if (h0out) h0out += (size_t)y*(BATCH*HID);

    int tid = threadIdx.x, lane = tid & 63, wid = tid >> 6;
    int wm = wid >> 1, wn = wid & 1;
    int row0 = wm*32 + (lane & 15);
    int col0 = nb*64 + wn*32 + (lane & 15);
    int kc = (lane >> 4)*8;
    const f16* a_base = A0 + row0*512 + kc;
    const f16* b_base = B + (size_t)col0*1024 + kc;

    floatx4 acc[2][2] = {};
    #pragma unroll
    for (int ks = 0; ks < 16; ks++){
        half8 af[2], bf[2];
        af[0] = *(const half8*)(a_base + ks*32);
        af[1] = *(const half8*)(a_base + 16*512 + ks*32);
        bf[0] = *(const half8*)(b_base + ks*32);
        bf[1] = *(const half8*)(b_base + (size_t)16*1024 + ks*32);
        MFMA4(af, bf);
    }

    __shared__ float Cl[128][65];
    int rr = (lane >> 4)*4;
    #pragma unroll
    for (int mi = 0; mi < 2; mi++)
    #pragma unroll
    for (int ni = 0; ni < 2; ni++){
        float bias = bsum_l[col0 + ni*16];
        #pragma unroll
        for (int j = 0; j < 4; j++)
            Cl[wm*32 + mi*16 + rr + j][wn*32 + ni*16 + (lane & 15)] = acc[mi][ni][j] + bias;
    }
    __syncthreads();

    #pragma unroll
    for (int it = 0; it < 4; it++){
        int item = tid + it*512;
        int b = item >> 4, hl = item & 15;
        float gi = Cl[b][hl*4+0];
        float gg = Cl[b][hl*4+2];
        float go = Cl[b][hl*4+3];
        int hg = nb*16 + hl;
        float cn = fsig(gi)*ftanh(gg);           // cprev == 0
        float hn = fsig(go)*ftanh(cn);
        size_t toff = (((size_t)y*NL + l)*BATCH + b)*HID + hg;
        htape16[toff] = (f16)hn;
        ctape[toff]   = cn;
        if (h0out) h0out[b*HID + hg] = (f16)hn;
    }
}

// ---------------- persistent scan kernel (plain launch, custom barrier) ----------------
// Split-K pipelined schedule (2 barriers/step, both halves overlapped):
//  Phase A(t): G0 finishes gemm_l0(t)  (dyn half: prevh16_l0, K 512..1023) + epilogue
//              G1 finishes gemm_l1(t-1)(dyn half: prevh16_l1) + epilogue -> out
//  Phase B(t): G0: attn_l0(t+1) + STATIC half of gemm_l0(t+1) (xsf, K 0..511)
//              G1: attn_l1(t)   + PREFETCH half of gemm_l1(t) (h016(t), K 0..511)
// Accumulators persist in VGPRs across one barrier. Accumulation order
// (K 0..511 then 512..1023) identical to the monolithic version.
struct SArgs {
    const f16* xsf; const f16* xattn; const f16* Wcat; const float* bsum;
    const float* whd; const float* whtd; const float* av;
    const f16* htape16; const float* ctape;   // ring init (k_fill output)
    float* prevc; f16* prevh16;
    f16* h016; float2* slotstage; float* out;
    unsigned* bar;
};

__global__ __launch_bounds__(256, 1) void k_scan(SArgs A)
{
    __shared__ f16 Wsh[16*1024];          // 32 KiB: this block's 16 gate-cols, XOR-swizzled
    __shared__ float2 stg[128*4];         // 4 KiB epilogue staging {h,c}
    __shared__ float wpart[TAPE][4];
    __shared__ unsigned ringH[TAPE][256]; // 30 KiB: tape h, packed f16x2 per thread
    __shared__ unsigned ringC[TAPE][256]; // 30 KiB: tape c, packed f16x2 per thread

    const int blk = blockIdx.x;
    const int tid = threadIdx.x;
    const int lane = tid & 63, wv = tid >> 6;
    const int myl = blk >> 7;           // 0: blocks 0..127 (gemm_l0 + attn_l0), 1: 128..255
    const int cb  = blk & 127;          // gemm: 16 gate-cols -> 4 h
    const int b   = blk & 127;          // attn: batch index
    const int h0  = tid*2;              // attn: h pair
    const size_t BH = (size_t)BATCH*HID;

    // ---- weights to LDS (once) ----
    {
        const f16* src = A.Wcat + ((size_t)myl*NG + (size_t)cb*16)*1024;
        for (int i = tid; i < 2048; i += 256){
            int c = i >> 7;              // 0..15
            int k = (i & 127)*8;
            int dst = (c << 10) | (k ^ ((c & 7) << 3));
            *(half8*)&Wsh[dst] = *(const half8*)(src + ((size_t)c << 10) + k);
        }
    }

    // ---- tape ring -> LDS (packed f16x2 per thread) ----
    float phx = 0.f, phy = 0.f;          // prev_h (this block's layer), lives in regs
    #pragma unroll
    for (int p = 0; p < TAPE; p++){
        size_t off = (((size_t)p*NL + myl)*BATCH + b)*HID + h0;
        ringH[p][tid] = *(const unsigned*)(A.htape16 + off);
        float2 cc = *(const float2*)(A.ctape + off);
        ringC[p][tid] = packh2(cc.x, cc.y);
    }
    __syncthreads();

    // ---- attention for this block's (myl, b) ----
    auto do_attn = [&](int t, bool consume){
        if (consume){
            int snew = (t-1) % TAPE;
            // cached float2 loads; fresh after gridbar's acquire fence
            const float2* sl2 = A.slotstage + ((size_t)myl*BATCH + b)*HID + h0;
            float2 c0 = sl2[0], c1 = sl2[1];
            ringH[snew][tid] = packh2(c0.x, c1.x);
            ringC[snew][tid] = packh2(c0.y, c1.y);
        }
        size_t pb = ((size_t)myl*BATCH + b)*HID + h0;
        unsigned xu = *(const unsigned*)(A.xattn + (((size_t)t*NL + myl)*BATCH + b)*HID + h0);
        float2 xa = unpackh2(xu);
        int hw = myl*HID + h0;
        float wdx = A.whd[hw],  wdy = A.whd[hw+1];
        float wtx = A.whtd[hw], wty = A.whtd[hw+1];
        float vvx = A.av[hw],   vvy = A.av[hw+1];
        float bx = xa.x + phx*wtx, by = xa.y + phy*wty;

        float sc[TAPE];
        #pragma unroll
        for (int p = 0; p < TAPE; p++){
            float2 hv = unpackh2(ringH[p][tid]);
            float ax = ftanh(hv.x*wdx + bx);
            float ay = ftanh(hv.y*wdy + by);
            float s = ax*vvx + ay*vvy;
            #pragma unroll
            for (int o = 32; o; o >>= 1) s += __shfl_xor(s, o);
            if (lane == 0) wpart[p][wv] = s;
        }
        __syncthreads();
        float m = -1e30f;
        #pragma unroll
        for (int p = 0; p < TAPE; p++){
            sc[p] = wpart[p][0] + wpart[p][1] + wpart[p][2] + wpart[p][3];
            m = fmaxf(m, sc[p]);
        }
        float Z = 0.f;
        #pragma unroll
        for (int p = 0; p < TAPE; p++){ sc[p] = __expf(sc[p] - m); Z += sc[p]; }
        float inv = 1.f/Z;
        float ahx=0.f, ahy=0.f, acx=0.f, acy=0.f;
        #pragma unroll
        for (int p = 0; p < TAPE; p++){
            float2 hv = unpackh2(ringH[p][tid]);
            float2 cv = unpackh2(ringC[p][tid]);
            ahx += sc[p]*hv.x; ahy += sc[p]*hv.y;
            acx += sc[p]*cv.x; acy += sc[p]*cv.y;
        }
        ahx*=inv; ahy*=inv; acx*=inv; acy*=inv;
        phx = ahx; phy = ahy;
        ast32(A.prevh16 + pb, packh2(ahx, ahy));
        union { float2 f; u64 u; } pc; pc.f.x = acx; pc.f.y = acy;
        ast64(A.prevc + pb, pc.u);
    };

    // ---- persistent GEMM accumulators (live across one barrier) ----
    floatx4 acc0 = {0,0,0,0}, acc1 = {0,0,0,0};
    const int colL = lane & 15;
    const int bofs = colL << 10;
    const int sw   = (colL & 7) << 3;
    const int rowT = wv*32;
    const int row0g = rowT + (lane & 15);
    const int kcl  = (lane >> 4)*8;
    const int rr   = (lane >> 4) << 2;
    const int hL   = colL >> 2;
    const int hG   = cb*4 + hL;

    // one 512-wide K half: 16 iters, A rows row0g/row0g+16, W cols from LDS
    auto gemm_half = [&](const f16* Abase, int kofs){
        const f16* a = Abase + (size_t)row0g*512 + kcl;
        #pragma unroll
        for (int ks = 0; ks < 16; ks++){
            half8 af0 = *(const half8*)(a + ks*32);
            half8 af1 = *(const half8*)(a + ks*32 + 16*512);
            int kx = (kcl + kofs + ks*32) ^ sw;
            half8 bf = *(const half8*)&Wsh[bofs + kx];
            acc0 = __builtin_amdgcn_mfma_f32_16x16x32_f16(af0, bf, acc0, 0, 0, 0);
            acc1 = __builtin_amdgcn_mfma_f32_16x16x32_f16(af1, bf, acc1, 0, 0, 0);
        }
    };

    // epilogue: quad-shfl gate transpose + cell update + publish; resets acc
    auto gemm_fin = [&](f16* h0out, float* outp){
        const float* cprev_l = A.prevc + (size_t)myl*BH;
        float cp[2][4];
        #pragma unroll
        for (int mi = 0; mi < 2; mi++)
        #pragma unroll
        for (int j = 0; j < 4; j++)
            cp[mi][j] = cprev_l[(size_t)(rowT + mi*16 + rr + j)*HID + hG];

        int baseLane = lane & 60;
        float bias = A.bsum[myl*NG + cb*16 + colL];
        #pragma unroll
        for (int mi = 0; mi < 2; mi++){
            #pragma unroll
            for (int j = 0; j < 4; j++){
                float g = (mi ? acc1[j] : acc0[j]) + bias;
                float gi = __shfl(g, baseLane+0);
                float gf = __shfl(g, baseLane+1);
                float gg = __shfl(g, baseLane+2);
                float go = __shfl(g, baseLane+3);
                int row = rowT + mi*16 + rr + j;
                float cn = fsig(gf)*cp[mi][j] + fsig(gi)*ftanh(gg);
                float hn = fsig(go)*ftanh(cn);
                if ((lane & 3) == 0){ float2 v; v.x=hn; v.y=cn; stg[row*4 + hL] = v; }
            }
        }
        __syncthreads();
        float2* slot2 = A.slotstage + (size_t)myl*BH;
        #pragma unroll
        for (int e = 0; e < 2; e++){
            int idx = tid + e*256;           // 0..511 = row*4 + hh
            int row = idx >> 2, hh = idx & 3;
            union { float2 f; u64 u; } cu; cu.f = stg[idx];
            ast64(&slot2[(size_t)row*HID + cb*4 + hh], cu.u);
        }
        if (tid < 128){
            int row = tid;
            if (myl == 0){
                union { f16 h[4]; u64 u; } pk;
                pk.h[0]=(f16)stg[row*4+0].x; pk.h[1]=(f16)stg[row*4+1].x;
                pk.h[2]=(f16)stg[row*4+2].x; pk.h[3]=(f16)stg[row*4+3].x;
                ast64(h0out + (size_t)row*512 + cb*4, pk.u);
            } else {
                union { float2 f; u64 u; } p0, p1;
                p0.f.x = stg[row*4+0].x; p0.f.y = stg[row*4+1].x;
                p1.f.x = stg[row*4+2].x; p1.f.y = stg[row*4+3].x;
                ast64(outp + (size_t)row*512 + cb*4,     p0.u);
                ast64(outp + (size_t)row*512 + cb*4 + 2, p1.u);
            }
        }
        floatx4 z = {0,0,0,0};
        acc0 = z; acc1 = z;
    };

    // ---- prologue phase: G0: attn_l0(TAPE) + static half gemm_l0(TAPE) ----
    if (myl == 0){
        do_attn(TAPE, false);
        gemm_half(A.xsf + (size_t)TAPE*BH, 0);
    }
    unsigned gen = 0;
    gridbar(A.bar, ++gen);

    // ---- main scan: 2 barriers / step ----
    for (int t = TAPE; t < SEQ; ++t){
        // Phase A(t): dynamic halves + epilogues
        if (myl == 0){
            gemm_half(A.prevh16, 512);                         // gemm_l0(t) dyn
            gemm_fin(A.h016, nullptr);                         // -> slot_l0(t), h016(t)
        } else if (t > TAPE){
            gemm_half(A.prevh16 + BH, 512);                    // gemm_l1(t-1) dyn
            gemm_fin(nullptr, A.out + (size_t)((t-1-16) % TAPE)*BH);
        }
        gridbar(A.bar, ++gen);
        // Phase B(t): attns + prefetchable halves
        if (myl == 0){
            if (t + 1 < SEQ){
                do_attn(t + 1, true);                          // attn_l0(t+1)
                gemm_half(A.xsf + (size_t)(t+1)*BH, 0);        // static half gemm_l0(t+1)
            }
        } else {
            do_attn(t, t > TAPE);                              // attn_l1(t)
            gemm_half(A.h016, 0);                              // h016 half gemm_l1(t)
        }
        gridbar(A.bar, ++gen);
    }
    // trailing: finish gemm_l1(SEQ-1)
    if (myl == 1){
        gemm_half(A.prevh16 + BH, 512);
        gemm_fin(nullptr, A.out + (size_t)((SEQ-1-16) % TAPE)*BH);
    }
}

// ---------------- host ----------------
extern "C" void kernel_launch(void* const* d_in, const int* in_sizes, int n_in,
                              void* d_out, int out_size, void* d_ws, size_t ws_size,
                              hipStream_t stream)
{
    (void)in_sizes; (void)n_in; (void)out_size; (void)ws_size;
    const float* xs       = (const float*)d_in[0];
    const float* W_ih     = (const float*)d_in[1];
    const float* W_hh     = (const float*)d_in[2];
    const float* b_ih     = (const float*)d_in[3];
    const float* b_hh     = (const float*)d_in[4];
    const float* attn_wh  = (const float*)d_in[5];
    const float* attn_wx  = (const float*)d_in[6];
    const float* attn_wht = (const float*)d_in[7];
    const float* attn_v   = (const float*)d_in[8];
    float* out = (float*)d_out;

    char* w = (char*)d_ws;
    auto alloc = [&](size_t bytes)->char*{ char* p = w; w += (bytes + 255) & ~(size_t)255; return p; };
    f16*   Wcat    = (f16*)   alloc((size_t)NL*NG*1024*2);
    float* bsum    = (float*) alloc((size_t)NL*NG*4);
    f16*   awx     = (f16*)   alloc((size_t)NL*HID*HID*2);
    float* whd     = (float*) alloc((size_t)NL*HID*4);
    float* whtd    = (float*) alloc((size_t)NL*HID*4);
    float* av      = (float*) alloc((size_t)NL*HID*4);
    f16*   xsf     = (f16*)   alloc((size_t)SEQ*BATCH*HID*2);
    f16*   xattn   = (f16*)   alloc((size_t)SEQ*NL*BATCH*HID*2);
    f16*   htape16 = (f16*)   alloc((size_t)TAPE*NL*BATCH*HID*2);
    float* ctape   = (float*) alloc((size_t)TAPE*NL*BATCH*HID*4);
    float* prevc   = (float*) alloc((size_t)NL*BATCH*HID*4);
    f16*   prevh16 = (f16*)   alloc((size_t)NL*BATCH*HID*2);
    f16*   h016    = (f16*)   alloc((size_t)BATCH*HID*2);
    f16*   h0all   = (f16*)   alloc((size_t)TAPE*BATCH*HID*2);
    float2* slotstage = (float2*)alloc((size_t)NL*BATCH*HID*8);
    unsigned* bar  = (unsigned*)alloc(4096);   // 16 leaves (128B apart) + root + rel

    hipMemsetAsync(prevc,   0, (size_t)NL*BATCH*HID*4, stream);
    hipMemsetAsync(prevh16, 0, (size_t)NL*BATCH*HID*2, stream);
    hipMemsetAsync(bar,     0, 4096, stream);

    k_setup_w   <<<dim3(16384), dim3(256), 0, stream>>>(W_ih, W_hh, b_ih, b_hh, Wcat, bsum);
    k_setup_misc<<<dim3(2048),  dim3(256), 0, stream>>>(attn_wx, attn_wh, attn_wht, attn_v, awx, whd, whtd, av);
    k_xs16      <<<dim3(16384), dim3(256), 0, stream>>>(xs, xsf);
    k_xattn     <<<dim3(8, SEQ, NL), dim3(512), 0, stream>>>(xsf, awx, xattn);

    k_fill<<<dim3(32, TAPE), dim3(512), 0, stream>>>(xsf, Wcat, bsum, htape16, ctape, 0, h0all);
    k_fill<<<dim3(32, TAPE), dim3(512), 0, stream>>>(h0all, Wcat + (size_t)NG*1024, bsum + NG,
                                                     htape16, ctape, 1, nullptr);

    // Plain (non-cooperative) launch: 256 blocks x 98.8 KiB LDS = 1 block/CU,
    // grid == #CUs -> all blocks co-resident by construction; capture-safe.
    SArgs sa;
    sa.xsf = xsf; sa.xattn = xattn; sa.Wcat = Wcat; sa.bsum = bsum;
    sa.whd = whd; sa.whtd = whtd; sa.av = av;
    sa.htape16 = htape16; sa.ctape = ctape;
    sa.prevc = prevc; sa.prevh16 = prevh16;
    sa.h016 = h016; sa.slotstage = slotstage; sa.out = out;
    sa.bar = bar;
    k_scan<<<dim3(NBLK), dim3(256), 0, stream>>>(sa);
}

// Round 13
// 7158.456 us; speedup vs baseline: 1.5340x; 1.0273x over previous
//
#include <hip/hip_runtime.h>
#include <hip/hip_fp16.h>

typedef _Float16 f16;
typedef _Float16 half8 __attribute__((ext_vector_type(8)));
typedef _Float16 half4v __attribute__((ext_vector_type(4)));
typedef float floatx4 __attribute__((ext_vector_type(4)));
typedef unsigned long long u64;

#define SEQ   256
#define BATCH 128
#define HID   512
#define NL    2
#define TAPE  30
#define NG    2048   // 4*HID
#define NBLK  256

__device__ __forceinline__ float fsig(float x)  { return 1.f/(1.f+__expf(-x)); }
__device__ __forceinline__ float ftanh(float x) { return 1.f - 2.f/(1.f+__expf(2.f*x)); }

// ---- agent-scope relaxed atomic STORES (sc1) — R10's proven protocol ----
__device__ __forceinline__ void ast64(void* p, u64 v){
    __hip_atomic_store((u64*)p, v, __ATOMIC_RELAXED, __HIP_MEMORY_SCOPE_AGENT);
}
__device__ __forceinline__ void ast32(void* p, unsigned v){
    __hip_atomic_store((unsigned*)p, v, __ATOMIC_RELAXED, __HIP_MEMORY_SCOPE_AGENT);
}
__device__ __forceinline__ unsigned packh2(float a, float b){
    union { f16 h[2]; unsigned u; } c; c.h[0]=(f16)a; c.h[1]=(f16)b; return c.u;
}
__device__ __forceinline__ float2 unpackh2(unsigned u){
    union { unsigned u; f16 h[2]; } c; c.u=u;
    float2 r; r.x=(float)c.h[0]; r.y=(float)c.h[1]; return r;
}

// ---- TREE grid barrier (R10): sc1 arrival tree + one acquire fence/block ----
#define BAR_ROOT 512
#define BAR_REL  544
__device__ __forceinline__ void gridbar(unsigned* bar, unsigned gen){
    __syncthreads();                  // drains vmcnt -> prior sc1 stores visible at L3
    if (threadIdx.x == 0){
        unsigned* leaf = bar + ((blockIdx.x >> 4) << 5);   // 16 blocks/leaf, 128B apart
        bool releaser = false;
        unsigned p = __hip_atomic_fetch_add(leaf, 1u, __ATOMIC_RELAXED, __HIP_MEMORY_SCOPE_AGENT);
        if ((p & 15u) == 15u){
            unsigned q = __hip_atomic_fetch_add(bar + BAR_ROOT, 1u, __ATOMIC_RELAXED, __HIP_MEMORY_SCOPE_AGENT);
            if ((q & 15u) == 15u){
                __hip_atomic_store(bar + BAR_REL, gen, __ATOMIC_RELAXED, __HIP_MEMORY_SCOPE_AGENT);
                releaser = true;
            }
        }
        if (!releaser){
            while (__hip_atomic_load(bar + BAR_REL, __ATOMIC_RELAXED, __HIP_MEMORY_SCOPE_AGENT) < gen){
                __builtin_amdgcn_s_sleep(8);
            }
        }
        __builtin_amdgcn_fence(__ATOMIC_ACQUIRE, "agent");   // one buffer_inv per block
    }
    __syncthreads();
}

// ---------------- setup: gate-permuted fp16 weights ----------------
__global__ void k_setup_w(const float* __restrict__ W_ih, const float* __restrict__ W_hh,
                          const float* __restrict__ b_ih, const float* __restrict__ b_hh,
                          f16* __restrict__ Wcat, float* __restrict__ bsum)
{
    int idx = blockIdx.x*256 + threadIdx.x;      // 2*2048*1024 threads
    int l = idx >> 21;
    int r = (idx >> 10) & 2047;
    int k = idx & 1023;
    int gate = r & 3, h = r >> 2;
    int orig = gate*HID + h;
    float wv = (k < 512) ? W_ih[((size_t)l*NG + orig)*512 + k]
                         : W_hh[((size_t)l*NG + orig)*512 + (k-512)];
    Wcat[idx] = (f16)wv;
    if (idx < NL*NG) {
        int l2 = idx >> 11, r2 = idx & 2047;
        int g2 = r2 & 3, h2 = r2 >> 2;
        int o2 = g2*HID + h2;
        bsum[idx] = b_ih[l2*NG + o2] + b_hh[l2*NG + o2];
    }
}

__global__ void k_setup_misc(const float* __restrict__ attn_wx, const float* __restrict__ attn_wh,
                             const float* __restrict__ attn_wht, const float* __restrict__ attn_v,
                             f16* __restrict__ awx, float* __restrict__ whd,
                             float* __restrict__ whtd, float* __restrict__ av)
{
    int idx = blockIdx.x*256 + threadIdx.x;      // 2*512*512 threads
    awx[idx] = (f16)attn_wx[idx];
    if (idx < NL*HID) {
        int l = idx >> 9, h = idx & 511;
        whd[idx]  = attn_wh[((size_t)l*HID + h)*HID + h];
        whtd[idx] = attn_wht[((size_t)l*HID + h)*HID + h];
        av[idx]   = attn_v[idx];
    }
}

__global__ void k_xs16(const float* __restrict__ x, f16* __restrict__ o)
{
    size_t i = ((size_t)blockIdx.x*256 + threadIdx.x)*4;
    float4 v = *(const float4*)(x + i);
    half4v h; h[0]=(f16)v.x; h[1]=(f16)v.y; h[2]=(f16)v.z; h[3]=(f16)v.w;
    *(half4v*)(o + i) = h;
}

#define MFMA4(af, bf) do { \
    acc[0][0] = __builtin_amdgcn_mfma_f32_16x16x32_f16(af[0], bf[0], acc[0][0], 0, 0, 0); \
    acc[0][1] = __builtin_amdgcn_mfma_f32_16x16x32_f16(af[0], bf[1], acc[0][1], 0, 0, 0); \
    acc[1][0] = __builtin_amdgcn_mfma_f32_16x16x32_f16(af[1], bf[0], acc[1][0], 0, 0, 0); \
    acc[1][1] = __builtin_amdgcn_mfma_f32_16x16x32_f16(af[1], bf[1], acc[1][1], 0, 0, 0); \
} while(0)

// ---------------- x_attn precompute ----------------
__global__ __launch_bounds__(512) void k_xattn(const f16* __restrict__ Xf,
                                               const f16* __restrict__ AWX,
                                               f16* __restrict__ XA)
{
    int nb = blockIdx.x;            // 0..7
    int t  = blockIdx.y;            // 0..255
    int l  = blockIdx.z;            // 0..1
    const f16* A  = Xf  + (size_t)t*(BATCH*512);
    const f16* Bm = AWX + (size_t)l*(512*512);
    int lane = threadIdx.x & 63, wid = threadIdx.x >> 6;
    int wm = wid >> 1, wn = wid & 1;
    int row0 = wm*32 + (lane & 15);
    int col0 = nb*64 + wn*32 + (lane & 15);
    int kc = (lane >> 4)*8;
    const f16* a_base = A  + row0*512 + kc;
    const f16* b_base = Bm + col0*512 + kc;
    floatx4 acc[2][2] = {};
    #pragma unroll 4
    for (int ks = 0; ks < 16; ks++){
        half8 af[2], bf[2];
        af[0] = *(const half8*)(a_base + ks*32);
        af[1] = *(const half8*)(a_base + 8192 + ks*32);
        bf[0] = *(const half8*)(b_base + ks*32);
        bf[1] = *(const half8*)(b_base + 8192 + ks*32);
        MFMA4(af, bf);
    }
    int rr = (lane >> 4)*4;
    #pragma unroll
    for (int mi = 0; mi < 2; mi++)
    #pragma unroll
    for (int ni = 0; ni < 2; ni++)
    #pragma unroll
    for (int j = 0; j < 4; j++){
        int brow = wm*32 + mi*16 + rr + j;
        int ch   = nb*64 + wn*32 + ni*16 + (lane & 15);
        XA[(((size_t)t*NL + l)*BATCH + brow)*HID + ch] = (f16)acc[mi][ni][j];
    }
}

// ---------------- tape fill (zero initial state, K=512) ----------------
__global__ __launch_bounds__(512) void k_fill(const f16* __restrict__ A0all,
                                              const f16* __restrict__ B,
                                              const float* __restrict__ bsum_l,
                                              f16* __restrict__ htape16, float* __restrict__ ctape,
                                              int l, f16* __restrict__ h0out)
{
    int y  = blockIdx.y;                         // step 0..29 (== slot)
    int nb = blockIdx.x;                         // 0..31
    const f16* A0 = A0all + (size_t)y*(BATCH*HID);
    if (h0out) h0out += (size_t)y*(BATCH*HID);

    int tid = threadIdx.x, lane = tid & 63, wid = tid >> 6;
    int wm = wid >> 1, wn = wid & 1;
    int row0 = wm*32 + (lane & 15);
    int col0 = nb*64 + wn*32 + (lane & 15);
    int kc = (lane >> 4)*8;
    const f16* a_base = A0 + row0*512 + kc;
    const f16* b_base = B + (size_t)col0*1024 + kc;

    floatx4 acc[2][2] = {};
    #pragma unroll
    for (int ks = 0; ks < 16; ks++){
        half8 af[2], bf[2];
        af[0] = *(const half8*)(a_base + ks*32);
        af[1] = *(const half8*)(a_base + 16*512 + ks*32);
        bf[0] = *(const half8*)(b_base + ks*32);
        bf[1] = *(const half8*)(b_base + (size_t)16*1024 + ks*32);
        MFMA4(af, bf);
    }

    __shared__ float Cl[128][65];
    int rr = (lane >> 4)*4;
    #pragma unroll
    for (int mi = 0; mi < 2; mi++)
    #pragma unroll
    for (int ni = 0; ni < 2; ni++){
        float bias = bsum_l[col0 + ni*16];
        #pragma unroll
        for (int j = 0; j < 4; j++)
            Cl[wm*32 + mi*16 + rr + j][wn*32 + ni*16 + (lane & 15)] = acc[mi][ni][j] + bias;
    }
    __syncthreads();

    #pragma unroll
    for (int it = 0; it < 4; it++){
        int item = tid + it*512;
        int b = item >> 4, hl = item & 15;
        float gi = Cl[b][hl*4+0];
        float gg = Cl[b][hl*4+2];
        float go = Cl[b][hl*4+3];
        int hg = nb*16 + hl;
        float cn = fsig(gi)*ftanh(gg);           // cprev == 0
        float hn = fsig(go)*ftanh(cn);
        size_t toff = (((size_t)y*NL + l)*BATCH + b)*HID + hg;
        htape16[toff] = (f16)hn;
        ctape[toff]   = cn;
        if (h0out) h0out[b*HID + hg] = (f16)hn;
    }
}

// ---------------- persistent scan kernel (plain launch, custom barrier) ----------------
// Split-K pipelined schedule (R12) + MLP-batched A loads (this round):
//  Phase A(t): G0 finishes gemm_l0(t)  (dyn half: prevh16_l0) + epilogue
//              G1 finishes gemm_l1(t-1)(dyn half: prevh16_l1) + epilogue -> out
//  Phase B(t): G0: attn_l0(t+1) + STATIC half of gemm_l0(t+1) (xsf)
//              G1: attn_l1(t)   + PREFETCH half of gemm_l1(t) (h016(t))
// gemm_half batches all 32 A-loads into registers BEFORE the MFMA chain so
// the post-inv L2 misses overlap into ONE L3 latency (MLP) instead of a
// serialized load->mfma->load chain. cprev loads issued at phase start.
struct SArgs {
    const f16* xsf; const f16* xattn; const f16* Wcat; const float* bsum;
    const float* whd; const float* whtd; const float* av;
    const f16* htape16; const float* ctape;   // ring init (k_fill output)
    float* prevc; f16* prevh16;
    f16* h016; float2* slotstage; float* out;
    unsigned* bar;
};

__global__ __launch_bounds__(256, 1) void k_scan(SArgs A)
{
    __shared__ f16 Wsh[16*1024];          // 32 KiB: this block's 16 gate-cols, XOR-swizzled
    __shared__ float2 stg[128*4];         // 4 KiB epilogue staging {h,c}
    __shared__ float wpart[TAPE][4];
    __shared__ unsigned ringH[TAPE][256]; // 30 KiB: tape h, packed f16x2 per thread
    __shared__ unsigned ringC[TAPE][256]; // 30 KiB: tape c, packed f16x2 per thread

    const int blk = blockIdx.x;
    const int tid = threadIdx.x;
    const int lane = tid & 63, wv = tid >> 6;
    const int myl = blk >> 7;           // 0: blocks 0..127 (gemm_l0 + attn_l0), 1: 128..255
    const int cb  = blk & 127;          // gemm: 16 gate-cols -> 4 h
    const int b   = blk & 127;          // attn: batch index
    const int h0  = tid*2;              // attn: h pair
    const size_t BH = (size_t)BATCH*HID;

    // ---- weights to LDS (once) ----
    {
        const f16* src = A.Wcat + ((size_t)myl*NG + (size_t)cb*16)*1024;
        for (int i = tid; i < 2048; i += 256){
            int c = i >> 7;              // 0..15
            int k = (i & 127)*8;
            int dst = (c << 10) | (k ^ ((c & 7) << 3));
            *(half8*)&Wsh[dst] = *(const half8*)(src + ((size_t)c << 10) + k);
        }
    }

    // ---- tape ring -> LDS (packed f16x2 per thread) ----
    float phx = 0.f, phy = 0.f;          // prev_h (this block's layer), lives in regs
    #pragma unroll
    for (int p = 0; p < TAPE; p++){
        size_t off = (((size_t)p*NL + myl)*BATCH + b)*HID + h0;
        ringH[p][tid] = *(const unsigned*)(A.htape16 + off);
        float2 cc = *(const float2*)(A.ctape + off);
        ringC[p][tid] = packh2(cc.x, cc.y);
    }
    __syncthreads();

    // ---- attention for this block's (myl, b) ----
    auto do_attn = [&](int t, bool consume){
        if (consume){
            int snew = (t-1) % TAPE;
            const float2* sl2 = A.slotstage + ((size_t)myl*BATCH + b)*HID + h0;
            float2 c0 = sl2[0], c1 = sl2[1];
            ringH[snew][tid] = packh2(c0.x, c1.x);
            ringC[snew][tid] = packh2(c0.y, c1.y);
        }
        size_t pb = ((size_t)myl*BATCH + b)*HID + h0;
        unsigned xu = *(const unsigned*)(A.xattn + (((size_t)t*NL + myl)*BATCH + b)*HID + h0);
        float2 xa = unpackh2(xu);
        int hw = myl*HID + h0;
        float wdx = A.whd[hw],  wdy = A.whd[hw+1];
        float wtx = A.whtd[hw], wty = A.whtd[hw+1];
        float vvx = A.av[hw],   vvy = A.av[hw+1];
        float bx = xa.x + phx*wtx, by = xa.y + phy*wty;

        float sc[TAPE];
        #pragma unroll
        for (int p = 0; p < TAPE; p++){
            float2 hv = unpackh2(ringH[p][tid]);
            float ax = ftanh(hv.x*wdx + bx);
            float ay = ftanh(hv.y*wdy + by);
            float s = ax*vvx + ay*vvy;
            #pragma unroll
            for (int o = 32; o; o >>= 1) s += __shfl_xor(s, o);
            if (lane == 0) wpart[p][wv] = s;
        }
        __syncthreads();
        float m = -1e30f;
        #pragma unroll
        for (int p = 0; p < TAPE; p++){
            sc[p] = wpart[p][0] + wpart[p][1] + wpart[p][2] + wpart[p][3];
            m = fmaxf(m, sc[p]);
        }
        float Z = 0.f;
        #pragma unroll
        for (int p = 0; p < TAPE; p++){ sc[p] = __expf(sc[p] - m); Z += sc[p]; }
        float inv = 1.f/Z;
        float ahx=0.f, ahy=0.f, acx=0.f, acy=0.f;
        #pragma unroll
        for (int p = 0; p < TAPE; p++){
            float2 hv = unpackh2(ringH[p][tid]);
            float2 cv = unpackh2(ringC[p][tid]);
            ahx += sc[p]*hv.x; ahy += sc[p]*hv.y;
            acx += sc[p]*cv.x; acy += sc[p]*cv.y;
        }
        ahx*=inv; ahy*=inv; acx*=inv; acy*=inv;
        phx = ahx; phy = ahy;
        ast32(A.prevh16 + pb, packh2(ahx, ahy));
        union { float2 f; u64 u; } pc; pc.f.x = acx; pc.f.y = acy;
        ast64(A.prevc + pb, pc.u);
    };

    // ---- persistent GEMM accumulators (live across one barrier) ----
    floatx4 acc0 = {0,0,0,0}, acc1 = {0,0,0,0};
    float cpv[2][4];                    // cprev, loaded at phase start
    const int colL = lane & 15;
    const int bofs = colL << 10;
    const int sw   = (colL & 7) << 3;
    const int rowT = wv*32;
    const int row0g = rowT + (lane & 15);
    const int kcl  = (lane >> 4)*8;
    const int rr   = (lane >> 4) << 2;
    const int hL   = colL >> 2;
    const int hG   = cb*4 + hL;

    auto load_cprev = [&](){
        const float* cprev_l = A.prevc + (size_t)myl*BH;
        #pragma unroll
        for (int mi = 0; mi < 2; mi++)
        #pragma unroll
        for (int j = 0; j < 4; j++)
            cpv[mi][j] = cprev_l[(size_t)(rowT + mi*16 + rr + j)*HID + hG];
    };

    // one 512-wide K half: batch ALL 32 A-loads, then 32 MFMAs (max MLP)
    auto gemm_half = [&](const f16* Abase, int kofs){
        const f16* a = Abase + (size_t)row0g*512 + kcl;
        half8 fa[16], fb[16];
        #pragma unroll
        for (int ks = 0; ks < 16; ks++){
            fa[ks] = *(const half8*)(a + ks*32);
            fb[ks] = *(const half8*)(a + ks*32 + 16*512);
        }
        #pragma unroll
        for (int ks = 0; ks < 16; ks++){
            int kx = (kcl + kofs + ks*32) ^ sw;
            half8 bf = *(const half8*)&Wsh[bofs + kx];
            acc0 = __builtin_amdgcn_mfma_f32_16x16x32_f16(fa[ks], bf, acc0, 0, 0, 0);
            acc1 = __builtin_amdgcn_mfma_f32_16x16x32_f16(fb[ks], bf, acc1, 0, 0, 0);
        }
    };

    // epilogue: quad-shfl gate transpose + cell update + publish; resets acc
    auto gemm_fin = [&](f16* h0out, float* outp){
        int baseLane = lane & 60;
        float bias = A.bsum[myl*NG + cb*16 + colL];
        #pragma unroll
        for (int mi = 0; mi < 2; mi++){
            #pragma unroll
            for (int j = 0; j < 4; j++){
                float g = (mi ? acc1[j] : acc0[j]) + bias;
                float gi = __shfl(g, baseLane+0);
                float gf = __shfl(g, baseLane+1);
                float gg = __shfl(g, baseLane+2);
                float go = __shfl(g, baseLane+3);
                int row = rowT + mi*16 + rr + j;
                float cn = fsig(gf)*cpv[mi][j] + fsig(gi)*ftanh(gg);
                float hn = fsig(go)*ftanh(cn);
                if ((lane & 3) == 0){ float2 v; v.x=hn; v.y=cn; stg[row*4 + hL] = v; }
            }
        }
        __syncthreads();
        float2* slot2 = A.slotstage + (size_t)myl*BH;
        #pragma unroll
        for (int e = 0; e < 2; e++){
            int idx = tid + e*256;           // 0..511 = row*4 + hh
            int row = idx >> 2, hh = idx & 3;
            union { float2 f; u64 u; } cu; cu.f = stg[idx];
            ast64(&slot2[(size_t)row*HID + cb*4 + hh], cu.u);
        }
        if (tid < 128){
            int row = tid;
            if (myl == 0){
                union { f16 h[4]; u64 u; } pk;
                pk.h[0]=(f16)stg[row*4+0].x; pk.h[1]=(f16)stg[row*4+1].x;
                pk.h[2]=(f16)stg[row*4+2].x; pk.h[3]=(f16)stg[row*4+3].x;
                ast64(h0out + (size_t)row*512 + cb*4, pk.u);
            } else {
                union { float2 f; u64 u; } p0, p1;
                p0.f.x = stg[row*4+0].x; p0.f.y = stg[row*4+1].x;
                p1.f.x = stg[row*4+2].x; p1.f.y = stg[row*4+3].x;
                ast64(outp + (size_t)row*512 + cb*4,     p0.u);
                ast64(outp + (size_t)row*512 + cb*4 + 2, p1.u);
            }
        }
        floatx4 z = {0,0,0,0};
        acc0 = z; acc1 = z;
    };

    // ---- prologue phase: G0: attn_l0(TAPE) + static half gemm_l0(TAPE) ----
    if (myl == 0){
        do_attn(TAPE, false);
        gemm_half(A.xsf + (size_t)TAPE*BH, 0);
    }
    unsigned gen = 0;
    gridbar(A.bar, ++gen);

    // ---- main scan: 2 barriers / step ----
    for (int t = TAPE; t < SEQ; ++t){
        // Phase A(t): dynamic halves + epilogues (cprev loads issued first)
        if (myl == 0){
            load_cprev();
            gemm_half(A.prevh16, 512);                         // gemm_l0(t) dyn
            gemm_fin(A.h016, nullptr);                         // -> slot_l0(t), h016(t)
        } else if (t > TAPE){
            load_cprev();
            gemm_half(A.prevh16 + BH, 512);                    // gemm_l1(t-1) dyn
            gemm_fin(nullptr, A.out + (size_t)((t-1-16) % TAPE)*BH);
        }
        gridbar(A.bar, ++gen);
        // Phase B(t): attns + prefetchable halves
        if (myl == 0){
            if (t + 1 < SEQ){
                do_attn(t + 1, true);                          // attn_l0(t+1)
                gemm_half(A.xsf + (size_t)(t+1)*BH, 0);        // static half gemm_l0(t+1)
            }
        } else {
            do_attn(t, t > TAPE);                              // attn_l1(t)
            gemm_half(A.h016, 0);                              // h016 half gemm_l1(t)
        }
        gridbar(A.bar, ++gen);
    }
    // trailing: finish gemm_l1(SEQ-1)
    if (myl == 1){
        load_cprev();
        gemm_half(A.prevh16 + BH, 512);
        gemm_fin(nullptr, A.out + (size_t)((SEQ-1-16) % TAPE)*BH);
    }
}

// ---------------- host ----------------
extern "C" void kernel_launch(void* const* d_in, const int* in_sizes, int n_in,
                              void* d_out, int out_size, void* d_ws, size_t ws_size,
                              hipStream_t stream)
{
    (void)in_sizes; (void)n_in; (void)out_size; (void)ws_size;
    const float* xs       = (const float*)d_in[0];
    const float* W_ih     = (const float*)d_in[1];
    const float* W_hh     = (const float*)d_in[2];
    const float* b_ih     = (const float*)d_in[3];
    const float* b_hh     = (const float*)d_in[4];
    const float* attn_wh  = (const float*)d_in[5];
    const float* attn_wx  = (const float*)d_in[6];
    const float* attn_wht = (const float*)d_in[7];
    const float* attn_v   = (const float*)d_in[8];
    float* out = (float*)d_out;

    char* w = (char*)d_ws;
    auto alloc = [&](size_t bytes)->char*{ char* p = w; w += (bytes + 255) & ~(size_t)255; return p; };
    f16*   Wcat    = (f16*)   alloc((size_t)NL*NG*1024*2);
    float* bsum    = (float*) alloc((size_t)NL*NG*4);
    f16*   awx     = (f16*)   alloc((size_t)NL*HID*HID*2);
    float* whd     = (float*) alloc((size_t)NL*HID*4);
    float* whtd    = (float*) alloc((size_t)NL*HID*4);
    float* av      = (float*) alloc((size_t)NL*HID*4);
    f16*   xsf     = (f16*)   alloc((size_t)SEQ*BATCH*HID*2);
    f16*   xattn   = (f16*)   alloc((size_t)SEQ*NL*BATCH*HID*2);
    f16*   htape16 = (f16*)   alloc((size_t)TAPE*NL*BATCH*HID*2);
    float* ctape   = (float*) alloc((size_t)TAPE*NL*BATCH*HID*4);
    float* prevc   = (float*) alloc((size_t)NL*BATCH*HID*4);
    f16*   prevh16 = (f16*)   alloc((size_t)NL*BATCH*HID*2);
    f16*   h016    = (f16*)   alloc((size_t)BATCH*HID*2);
    f16*   h0all   = (f16*)   alloc((size_t)TAPE*BATCH*HID*2);
    float2* slotstage = (float2*)alloc((size_t)NL*BATCH*HID*8);
    unsigned* bar  = (unsigned*)alloc(4096);   // 16 leaves (128B apart) + root + rel

    hipMemsetAsync(prevc,   0, (size_t)NL*BATCH*HID*4, stream);
    hipMemsetAsync(prevh16, 0, (size_t)NL*BATCH*HID*2, stream);
    hipMemsetAsync(bar,     0, 4096, stream);

    k_setup_w   <<<dim3(16384), dim3(256), 0, stream>>>(W_ih, W_hh, b_ih, b_hh, Wcat, bsum);
    k_setup_misc<<<dim3(2048),  dim3(256), 0, stream>>>(attn_wx, attn_wh, attn_wht, attn_v, awx, whd, whtd, av);
    k_xs16      <<<dim3(16384), dim3(256), 0, stream>>>(xs, xsf);
    k_xattn     <<<dim3(8, SEQ, NL), dim3(512), 0, stream>>>(xsf, awx, xattn);

    k_fill<<<dim3(32, TAPE), dim3(512), 0, stream>>>(xsf, Wcat, bsum, htape16, ctape, 0, h0all);
    k_fill<<<dim3(32, TAPE), dim3(512), 0, stream>>>(h0all, Wcat + (size_t)NG*1024, bsum + NG,
                                                     htape16, ctape, 1, nullptr);

    // Plain (non-cooperative) launch: 256 blocks x 98.8 KiB LDS = 1 block/CU,
    // grid == #CUs -> all blocks co-resident by construction; capture-safe.
    SArgs sa;
    sa.xsf = xsf; sa.xattn = xattn; sa.Wcat = Wcat; sa.bsum = bsum;
    sa.whd = whd; sa.whtd = whtd; sa.av = av;
    sa.htape16 = htape16; sa.ctape = ctape;
    sa.prevc = prevc; sa.prevh16 = prevh16;
    sa.h016 = h016; sa.slotstage = slotstage; sa.out = out;
    sa.bar = bar;
    k_scan<<<dim3(NBLK), dim3(256), 0, stream>>>(sa);
}

// Round 14
// 6413.628 us; speedup vs baseline: 1.7122x; 1.1161x over previous
//
#include <hip/hip_runtime.h>
#include <hip/hip_fp16.h>

typedef _Float16 f16;
typedef _Float16 half8 __attribute__((ext_vector_type(8)));
typedef _Float16 half4v __attribute__((ext_vector_type(4)));
typedef float floatx4 __attribute__((ext_vector_type(4)));
typedef unsigned long long u64;

#define SEQ   256
#define BATCH 128
#define HID   512
#define NL    2
#define TAPE  30
#define NG    2048   // 4*HID
#define NBLK  256

__device__ __forceinline__ float fsig(float x)  { return 1.f/(1.f+__expf(-x)); }
__device__ __forceinline__ float ftanh(float x) { return 1.f - 2.f/(1.f+__expf(2.f*x)); }

// ---- agent-scope relaxed atomic STORES (sc1) — R10's proven protocol ----
__device__ __forceinline__ void ast64(void* p, u64 v){
    __hip_atomic_store((u64*)p, v, __ATOMIC_RELAXED, __HIP_MEMORY_SCOPE_AGENT);
}
__device__ __forceinline__ void ast32(void* p, unsigned v){
    __hip_atomic_store((unsigned*)p, v, __ATOMIC_RELAXED, __HIP_MEMORY_SCOPE_AGENT);
}
__device__ __forceinline__ unsigned packh2(float a, float b){
    union { f16 h[2]; unsigned u; } c; c.h[0]=(f16)a; c.h[1]=(f16)b; return c.u;
}
__device__ __forceinline__ float2 unpackh2(unsigned u){
    union { unsigned u; f16 h[2]; } c; c.u=u;
    float2 r; r.x=(float)c.h[0]; r.y=(float)c.h[1]; return r;
}

// ---- SPLIT tree grid barrier: arrive-early / shadow work / wait-late ----
// Arrival tree (R10): 16 leaves (128B apart) x 16 blocks -> root -> release
// word. Counters monotonic; (count & 15)==15 marks last arrival. The LAST
// arriving block performs the release inside bar_arrive, so shadow work done
// by other blocks between arrive and wait never delays the release.
// bar_wait: thread0 polls release (s_sleep(2)), then ONE acquire fence
// (buffer_inv) per block so cached loads observe sc1-published data.
#define BAR_ROOT 512
#define BAR_REL  544
__device__ __forceinline__ void bar_arrive(unsigned* bar, unsigned gen){
    __syncthreads();                  // drains vmcnt -> prior sc1 stores visible at L3
    if (threadIdx.x == 0){
        unsigned* leaf = bar + ((blockIdx.x >> 4) << 5);   // 16 blocks/leaf
        unsigned p = __hip_atomic_fetch_add(leaf, 1u, __ATOMIC_RELAXED, __HIP_MEMORY_SCOPE_AGENT);
        if ((p & 15u) == 15u){
            unsigned q = __hip_atomic_fetch_add(bar + BAR_ROOT, 1u, __ATOMIC_RELAXED, __HIP_MEMORY_SCOPE_AGENT);
            if ((q & 15u) == 15u){
                __hip_atomic_store(bar + BAR_REL, gen, __ATOMIC_RELAXED, __HIP_MEMORY_SCOPE_AGENT);
            }
        }
    }
}
__device__ __forceinline__ void bar_wait(unsigned* bar, unsigned gen){
    if (threadIdx.x == 0){
        while (__hip_atomic_load(bar + BAR_REL, __ATOMIC_RELAXED, __HIP_MEMORY_SCOPE_AGENT) < gen){
            __builtin_amdgcn_s_sleep(2);
        }
        __builtin_amdgcn_fence(__ATOMIC_ACQUIRE, "agent");   // one buffer_inv per block
    }
    __syncthreads();
}

// ---------------- setup: gate-permuted fp16 weights ----------------
__global__ void k_setup_w(const float* __restrict__ W_ih, const float* __restrict__ W_hh,
                          const float* __restrict__ b_ih, const float* __restrict__ b_hh,
                          f16* __restrict__ Wcat, float* __restrict__ bsum)
{
    int idx = blockIdx.x*256 + threadIdx.x;      // 2*2048*1024 threads
    int l = idx >> 21;
    int r = (idx >> 10) & 2047;
    int k = idx & 1023;
    int gate = r & 3, h = r >> 2;
    int orig = gate*HID + h;
    float wv = (k < 512) ? W_ih[((size_t)l*NG + orig)*512 + k]
                         : W_hh[((size_t)l*NG + orig)*512 + (k-512)];
    Wcat[idx] = (f16)wv;
    if (idx < NL*NG) {
        int l2 = idx >> 11, r2 = idx & 2047;
        int g2 = r2 & 3, h2 = r2 >> 2;
        int o2 = g2*HID + h2;
        bsum[idx] = b_ih[l2*NG + o2] + b_hh[l2*NG + o2];
    }
}

__global__ void k_setup_misc(const float* __restrict__ attn_wx, const float* __restrict__ attn_wh,
                             const float* __restrict__ attn_wht, const float* __restrict__ attn_v,
                             f16* __restrict__ awx, float* __restrict__ whd,
                             float* __restrict__ whtd, float* __restrict__ av)
{
    int idx = blockIdx.x*256 + threadIdx.x;      // 2*512*512 threads
    awx[idx] = (f16)attn_wx[idx];
    if (idx < NL*HID) {
        int l = idx >> 9, h = idx & 511;
        whd[idx]  = attn_wh[((size_t)l*HID + h)*HID + h];
        whtd[idx] = attn_wht[((size_t)l*HID + h)*HID + h];
        av[idx]   = attn_v[idx];
    }
}

__global__ void k_xs16(const float* __restrict__ x, f16* __restrict__ o)
{
    size_t i = ((size_t)blockIdx.x*256 + threadIdx.x)*4;
    float4 v = *(const float4*)(x + i);
    half4v h; h[0]=(f16)v.x; h[1]=(f16)v.y; h[2]=(f16)v.z; h[3]=(f16)v.w;
    *(half4v*)(o + i) = h;
}

#define MFMA4(af, bf) do { \
    acc[0][0] = __builtin_amdgcn_mfma_f32_16x16x32_f16(af[0], bf[0], acc[0][0], 0, 0, 0); \
    acc[0][1] = __builtin_amdgcn_mfma_f32_16x16x32_f16(af[0], bf[1], acc[0][1], 0, 0, 0); \
    acc[1][0] = __builtin_amdgcn_mfma_f32_16x16x32_f16(af[1], bf[0], acc[1][0], 0, 0, 0); \
    acc[1][1] = __builtin_amdgcn_mfma_f32_16x16x32_f16(af[1], bf[1], acc[1][1], 0, 0, 0); \
} while(0)

// ---------------- x_attn precompute ----------------
__global__ __launch_bounds__(512) void k_xattn(const f16* __restrict__ Xf,
                                               const f16* __restrict__ AWX,
                                               f16* __restrict__ XA)
{
    int nb = blockIdx.x;            // 0..7
    int t  = blockIdx.y;            // 0..255
    int l  = blockIdx.z;            // 0..1
    const f16* A  = Xf  + (size_t)t*(BATCH*512);
    const f16* Bm = AWX + (size_t)l*(512*512);
    int lane = threadIdx.x & 63, wid = threadIdx.x >> 6;
    int wm = wid >> 1, wn = wid & 1;
    int row0 = wm*32 + (lane & 15);
    int col0 = nb*64 + wn*32 + (lane & 15);
    int kc = (lane >> 4)*8;
    const f16* a_base = A  + row0*512 + kc;
    const f16* b_base = Bm + col0*512 + kc;
    floatx4 acc[2][2] = {};
    #pragma unroll 4
    for (int ks = 0; ks < 16; ks++){
        half8 af[2], bf[2];
        af[0] = *(const half8*)(a_base + ks*32);
        af[1] = *(const half8*)(a_base + 8192 + ks*32);
        bf[0] = *(const half8*)(b_base + ks*32);
        bf[1] = *(const half8*)(b_base + 8192 + ks*32);
        MFMA4(af, bf);
    }
    int rr = (lane >> 4)*4;
    #pragma unroll
    for (int mi = 0; mi < 2; mi++)
    #pragma unroll
    for (int ni = 0; ni < 2; ni++)
    #pragma unroll
    for (int j = 0; j < 4; j++){
        int brow = wm*32 + mi*16 + rr + j;
        int ch   = nb*64 + wn*32 + ni*16 + (lane & 15);
        XA[(((size_t)t*NL + l)*BATCH + brow)*HID + ch] = (f16)acc[mi][ni][j];
    }
}

// ---------------- tape fill (zero initial state, K=512) ----------------
__global__ __launch_bounds__(512) void k_fill(const f16* __restrict__ A0all,
                                              const f16* __restrict__ B,
                                              const float* __restrict__ bsum_l,
                                              f16* __restrict__ htape16, float* __restrict__ ctape,
                                              int l, f16* __restrict__ h0out)
{
    int y  = blockIdx.y;                         // step 0..29 (== slot)
    int nb = blockIdx.x;                         // 0..31
    const f16* A0 = A0all + (size_t)y*(BATCH*HID);
    if (h0out) h0out += (size_t)y*(BATCH*HID);

    int tid = threadIdx.x, lane = tid & 63, wid = tid >> 6;
    int wm = wid >> 1, wn = wid & 1;
    int row0 = wm*32 + (lane & 15);
    int col0 = nb*64 + wn*32 + (lane & 15);
    int kc = (lane >> 4)*8;
    const f16* a_base = A0 + row0*512 + kc;
    const f16* b_base = B + (size_t)col0*1024 + kc;

    floatx4 acc[2][2] = {};
    #pragma unroll
    for (int ks = 0; ks < 16; ks++){
        half8 af[2], bf[2];
        af[0] = *(const half8*)(a_base + ks*32);
        af[1] = *(const half8*)(a_base + 16*512 + ks*32);
        bf[0] = *(const half8*)(b_base + ks*32);
        bf[1] = *(const half8*)(b_base + (size_t)16*1024 + ks*32);
        MFMA4(af, bf);
    }

    __shared__ float Cl[128][65];
    int rr = (lane >> 4)*4;
    #pragma unroll
    for (int mi = 0; mi < 2; mi++)
    #pragma unroll
    for (int ni = 0; ni < 2; ni++){
        float bias = bsum_l[col0 + ni*16];
        #pragma unroll
        for (int j = 0; j < 4; j++)
            Cl[wm*32 + mi*16 + rr + j][wn*32 + ni*16 + (lane & 15)] = acc[mi][ni][j] + bias;
    }
    __syncthreads();

    #pragma unroll
    for (int it = 0; it < 4; it++){
        int item = tid + it*512;
        int b = item >> 4, hl = item & 15;
        float gi = Cl[b][hl*4+0];
        float gg = Cl[b][hl*4+2];
        float go = Cl[b][hl*4+3];
        int hg = nb*16 + hl;
        float cn = fsig(gi)*ftanh(gg);           // cprev == 0
        float hn = fsig(go)*ftanh(cn);
        size_t toff = (((size_t)y*NL + l)*BATCH + b)*HID + hg;
        htape16[toff] = (f16)hn;
        ctape[toff]   = cn;
        if (h0out) h0out[b*HID + hg] = (f16)hn;
    }
}

// ---------------- persistent scan kernel (plain launch, split barrier) ----------------
// Arrive-early/wait-late schedule:
//  Phase A(t): G0: gemm_l0(t) dyn half + fin (publish slot_l0(t), h016(t)); arrive;
//                  [shadow] attn_pre_l0(t+1): 29 old-slot scores;            wait.
//              G1: (t>TAPE) gemm_l1(t-1) dyn half + fin (publish slot, out); arrive;
//                  [shadow] attn_pre_l1(t);                                  wait.
//  Phase B(t): G0: attn_post_l0(t+1): consume slot, softmax, publish prevh/c; arrive;
//                  [shadow] static half gemm_l0(t+1) (xsf, read-only);        wait.
//              G1: attn_post_l1(t); arrive;
//                  [shadow] h016 half gemm_l1(t) (fenced at barrier A);       wait.
struct SArgs {
    const f16* xsf; const f16* xattn; const f16* Wcat; const float* bsum;
    const float* whd; const float* whtd; const float* av;
    const f16* htape16; const float* ctape;   // ring init (k_fill output)
    float* prevc; f16* prevh16;
    f16* h016; float2* slotstage; float* out;
    unsigned* bar;
};

__global__ __launch_bounds__(256, 1) void k_scan(SArgs A)
{
    __shared__ f16 Wsh[16*1024];          // 32 KiB: this block's 16 gate-cols, XOR-swizzled
    __shared__ float2 stg[128*4];         // 4 KiB epilogue staging {h,c}
    __shared__ float wpart[TAPE][4];
    __shared__ unsigned ringH[TAPE][256]; // 30 KiB: tape h, packed f16x2 per thread
    __shared__ unsigned ringC[TAPE][256]; // 30 KiB: tape c, packed f16x2 per thread

    const int blk = blockIdx.x;
    const int tid = threadIdx.x;
    const int lane = tid & 63, wv = tid >> 6;
    const int myl = blk >> 7;           // 0: blocks 0..127 (gemm_l0 + attn_l0), 1: 128..255
    const int cb  = blk & 127;          // gemm: 16 gate-cols -> 4 h
    const int b   = blk & 127;          // attn: batch index
    const int h0  = tid*2;              // attn: h pair
    const size_t BH = (size_t)BATCH*HID;

    // ---- weights to LDS (once) ----
    {
        const f16* src = A.Wcat + ((size_t)myl*NG + (size_t)cb*16)*1024;
        for (int i = tid; i < 2048; i += 256){
            int c = i >> 7;              // 0..15
            int k = (i & 127)*8;
            int dst = (c << 10) | (k ^ ((c & 7) << 3));
            *(half8*)&Wsh[dst] = *(const half8*)(src + ((size_t)c << 10) + k);
        }
    }

    // ---- tape ring -> LDS (packed f16x2 per thread) ----
    float phx = 0.f, phy = 0.f;          // prev_h (this block's layer), lives in regs
    #pragma unroll
    for (int p = 0; p < TAPE; p++){
        size_t off = (((size_t)p*NL + myl)*BATCH + b)*HID + h0;
        ringH[p][tid] = *(const unsigned*)(A.htape16 + off);
        float2 cc = *(const float2*)(A.ctape + off);
        ringC[p][tid] = packh2(cc.x, cc.y);
    }
    __syncthreads();

    // ---- attention state persisting from pre to post (registers) ----
    float p_wdx, p_wdy, p_vvx, p_vvy, p_bx, p_by;

    // pre: everything that does NOT depend on the new tape slot.
    // Reads xattn (read-only), prev_h (regs), old 29 ring slots (local LDS).
    auto attn_pre = [&](int t, int snew){
        unsigned xu = *(const unsigned*)(A.xattn + (((size_t)t*NL + myl)*BATCH + b)*HID + h0);
        float2 xa = unpackh2(xu);
        int hw = myl*HID + h0;
        p_wdx = A.whd[hw];  p_wdy = A.whd[hw+1];
        float wtx = A.whtd[hw], wty = A.whtd[hw+1];
        p_vvx = A.av[hw];   p_vvy = A.av[hw+1];
        p_bx = xa.x + phx*wtx;
        p_by = xa.y + phy*wty;
        #pragma unroll
        for (int p = 0; p < TAPE; p++){
            if (p != snew){                  // uniform branch (snew is block-uniform)
                float2 hv = unpackh2(ringH[p][tid]);
                float ax = ftanh(hv.x*p_wdx + p_bx);
                float ay = ftanh(hv.y*p_wdy + p_by);
                float s = ax*p_vvx + ay*p_vvy;
                #pragma unroll
                for (int o = 32; o; o >>= 1) s += __shfl_xor(s, o);
                if (lane == 0) wpart[p][wv] = s;
            }
        }
    };

    // post: consume new slot (fenced), final score, softmax, weighted sums, publish.
    auto attn_post = [&](int snew){
        size_t pb = ((size_t)myl*BATCH + b)*HID + h0;
        if (snew >= 0){
            const float2* sl2 = A.slotstage + ((size_t)myl*BATCH + b)*HID + h0;
            float2 c0 = sl2[0], c1 = sl2[1];
            unsigned nh = packh2(c0.x, c1.x);
            unsigned nc = packh2(c0.y, c1.y);
            ringH[snew][tid] = nh;           // runtime-indexed LDS store: fine
            ringC[snew][tid] = nc;
            float2 hv = unpackh2(nh);
            float ax = ftanh(hv.x*p_wdx + p_bx);
            float ay = ftanh(hv.y*p_wdy + p_by);
            float s = ax*p_vvx + ay*p_vvy;
            #pragma unroll
            for (int o = 32; o; o >>= 1) s += __shfl_xor(s, o);
            if (lane == 0) wpart[snew][wv] = s;
        }
        __syncthreads();
        float sc[TAPE]; float m = -1e30f;
        #pragma unroll
        for (int p = 0; p < TAPE; p++){
            sc[p] = wpart[p][0] + wpart[p][1] + wpart[p][2] + wpart[p][3];
            m = fmaxf(m, sc[p]);
        }
        float Z = 0.f;
        #pragma unroll
        for (int p = 0; p < TAPE; p++){ sc[p] = __expf(sc[p] - m); Z += sc[p]; }
        float inv = 1.f/Z;
        float ahx=0.f, ahy=0.f, acx=0.f, acy=0.f;
        #pragma unroll
        for (int p = 0; p < TAPE; p++){
            float2 hv = unpackh2(ringH[p][tid]);
            float2 cv = unpackh2(ringC[p][tid]);
            ahx += sc[p]*hv.x; ahy += sc[p]*hv.y;
            acx += sc[p]*cv.x; acy += sc[p]*cv.y;
        }
        ahx*=inv; ahy*=inv; acx*=inv; acy*=inv;
        phx = ahx; phy = ahy;
        ast32(A.prevh16 + pb, packh2(ahx, ahy));
        union { float2 f; u64 u; } pc; pc.f.x = acx; pc.f.y = acy;
        ast64(A.prevc + pb, pc.u);
    };

    // ---- persistent GEMM accumulators (live across barriers) ----
    floatx4 acc0 = {0,0,0,0}, acc1 = {0,0,0,0};
    float cpv[2][4];                    // cprev, loaded at phase start
    const int colL = lane & 15;
    const int bofs = colL << 10;
    const int sw   = (colL & 7) << 3;
    const int rowT = wv*32;
    const int row0g = rowT + (lane & 15);
    const int kcl  = (lane >> 4)*8;
    const int rr   = (lane >> 4) << 2;
    const int hL   = colL >> 2;
    const int hG   = cb*4 + hL;

    auto load_cprev = [&](){
        const float* cprev_l = A.prevc + (size_t)myl*BH;
        #pragma unroll
        for (int mi = 0; mi < 2; mi++)
        #pragma unroll
        for (int j = 0; j < 4; j++)
            cpv[mi][j] = cprev_l[(size_t)(rowT + mi*16 + rr + j)*HID + hG];
    };

    // one 512-wide K half: batch ALL 32 A-loads, then 32 MFMAs (MLP)
    auto gemm_half = [&](const f16* Abase, int kofs){
        const f16* a = Abase + (size_t)row0g*512 + kcl;
        half8 fa[16], fb[16];
        #pragma unroll
        for (int ks = 0; ks < 16; ks++){
            fa[ks] = *(const half8*)(a + ks*32);
            fb[ks] = *(const half8*)(a + ks*32 + 16*512);
        }
        #pragma unroll
        for (int ks = 0; ks < 16; ks++){
            int kx = (kcl + kofs + ks*32) ^ sw;
            half8 bf = *(const half8*)&Wsh[bofs + kx];
            acc0 = __builtin_amdgcn_mfma_f32_16x16x32_f16(fa[ks], bf, acc0, 0, 0, 0);
            acc1 = __builtin_amdgcn_mfma_f32_16x16x32_f16(fb[ks], bf, acc1, 0, 0, 0);
        }
    };

    // epilogue: quad-shfl gate transpose + cell update + publish; resets acc
    auto gemm_fin = [&](f16* h0out, float* outp){
        int baseLane = lane & 60;
        float bias = A.bsum[myl*NG + cb*16 + colL];
        #pragma unroll
        for (int mi = 0; mi < 2; mi++){
            #pragma unroll
            for (int j = 0; j < 4; j++){
                float g = (mi ? acc1[j] : acc0[j]) + bias;
                float gi = __shfl(g, baseLane+0);
                float gf = __shfl(g, baseLane+1);
                float gg = __shfl(g, baseLane+2);
                float go = __shfl(g, baseLane+3);
                int row = rowT + mi*16 + rr + j;
                float cn = fsig(gf)*cpv[mi][j] + fsig(gi)*ftanh(gg);
                float hn = fsig(go)*ftanh(cn);
                if ((lane & 3) == 0){ float2 v; v.x=hn; v.y=cn; stg[row*4 + hL] = v; }
            }
        }
        __syncthreads();
        float2* slot2 = A.slotstage + (size_t)myl*BH;
        #pragma unroll
        for (int e = 0; e < 2; e++){
            int idx = tid + e*256;           // 0..511 = row*4 + hh
            int row = idx >> 2, hh = idx & 3;
            union { float2 f; u64 u; } cu; cu.f = stg[idx];
            ast64(&slot2[(size_t)row*HID + cb*4 + hh], cu.u);
        }
        if (tid < 128){
            int row = tid;
            if (myl == 0){
                union { f16 h[4]; u64 u; } pk;
                pk.h[0]=(f16)stg[row*4+0].x; pk.h[1]=(f16)stg[row*4+1].x;
                pk.h[2]=(f16)stg[row*4+2].x; pk.h[3]=(f16)stg[row*4+3].x;
                ast64(h0out + (size_t)row*512 + cb*4, pk.u);
            } else {
                union { float2 f; u64 u; } p0, p1;
                p0.f.x = stg[row*4+0].x; p0.f.y = stg[row*4+1].x;
                p1.f.x = stg[row*4+2].x; p1.f.y = stg[row*4+3].x;
                ast64(outp + (size_t)row*512 + cb*4,     p0.u);
                ast64(outp + (size_t)row*512 + cb*4 + 2, p1.u);
            }
        }
        floatx4 z = {0,0,0,0};
        acc0 = z; acc1 = z;
    };

    // ---- prologue: G0 computes attn_l0(TAPE) fully + static half; barrier ----
    unsigned gen = 0;
    if (myl == 0){
        attn_pre(TAPE, -1);
        attn_post(-1);                        // publish prevh_l0(TAPE), prevc_l0(TAPE)
        gemm_half(A.xsf + (size_t)TAPE*BH, 0);
    }
    ++gen; bar_arrive(A.bar, gen); bar_wait(A.bar, gen);

    // ---- main scan: 2 split barriers / step ----
    for (int t = TAPE; t < SEQ; ++t){
        // Phase A(t)
        if (myl == 0){
            load_cprev();
            gemm_half(A.prevh16, 512);                         // gemm_l0(t) dyn
            gemm_fin(A.h016, nullptr);                         // publish slot_l0(t), h016(t)
            ++gen; bar_arrive(A.bar, gen);
            if (t + 1 < SEQ) attn_pre(t + 1, t % TAPE);        // shadow
        } else {
            if (t > TAPE){
                load_cprev();
                gemm_half(A.prevh16 + BH, 512);                // gemm_l1(t-1) dyn
                gemm_fin(nullptr, A.out + (size_t)((t-1-16) % TAPE)*BH);
            }
            ++gen; bar_arrive(A.bar, gen);
            attn_pre(t, t > TAPE ? (t-1) % TAPE : -1);         // shadow
        }
        bar_wait(A.bar, gen);
        // Phase B(t)
        if (myl == 0){
            if (t + 1 < SEQ) attn_post(t % TAPE);              // attn_l0(t+1)
            ++gen; bar_arrive(A.bar, gen);
            if (t + 1 < SEQ) gemm_half(A.xsf + (size_t)(t+1)*BH, 0);  // shadow (static)
        } else {
            attn_post(t > TAPE ? (t-1) % TAPE : -1);           // attn_l1(t)
            ++gen; bar_arrive(A.bar, gen);
            gemm_half(A.h016, 0);                              // shadow (fenced at bar A)
        }
        bar_wait(A.bar, gen);
    }
    // trailing: finish gemm_l1(SEQ-1)
    if (myl == 1){
        load_cprev();
        gemm_half(A.prevh16 + BH, 512);
        gemm_fin(nullptr, A.out + (size_t)((SEQ-1-16) % TAPE)*BH);
    }
}

// ---------------- host ----------------
extern "C" void kernel_launch(void* const* d_in, const int* in_sizes, int n_in,
                              void* d_out, int out_size, void* d_ws, size_t ws_size,
                              hipStream_t stream)
{
    (void)in_sizes; (void)n_in; (void)out_size; (void)ws_size;
    const float* xs       = (const float*)d_in[0];
    const float* W_ih     = (const float*)d_in[1];
    const float* W_hh     = (const float*)d_in[2];
    const float* b_ih     = (const float*)d_in[3];
    const float* b_hh     = (const float*)d_in[4];
    const float* attn_wh  = (const float*)d_in[5];
    const float* attn_wx  = (const float*)d_in[6];
    const float* attn_wht = (const float*)d_in[7];
    const float* attn_v   = (const float*)d_in[8];
    float* out = (float*)d_out;

    char* w = (char*)d_ws;
    auto alloc = [&](size_t bytes)->char*{ char* p = w; w += (bytes + 255) & ~(size_t)255; return p; };
    f16*   Wcat    = (f16*)   alloc((size_t)NL*NG*1024*2);
    float* bsum    = (float*) alloc((size_t)NL*NG*4);
    f16*   awx     = (f16*)   alloc((size_t)NL*HID*HID*2);
    float* whd     = (float*) alloc((size_t)NL*HID*4);
    float* whtd    = (float*) alloc((size_t)NL*HID*4);
    float* av      = (float*) alloc((size_t)NL*HID*4);
    f16*   xsf     = (f16*)   alloc((size_t)SEQ*BATCH*HID*2);
    f16*   xattn   = (f16*)   alloc((size_t)SEQ*NL*BATCH*HID*2);
    f16*   htape16 = (f16*)   alloc((size_t)TAPE*NL*BATCH*HID*2);
    float* ctape   = (float*) alloc((size_t)TAPE*NL*BATCH*HID*4);
    float* prevc   = (float*) alloc((size_t)NL*BATCH*HID*4);
    f16*   prevh16 = (f16*)   alloc((size_t)NL*BATCH*HID*2);
    f16*   h016    = (f16*)   alloc((size_t)BATCH*HID*2);
    f16*   h0all   = (f16*)   alloc((size_t)TAPE*BATCH*HID*2);
    float2* slotstage = (float2*)alloc((size_t)NL*BATCH*HID*8);
    unsigned* bar  = (unsigned*)alloc(4096);   // 16 leaves (128B apart) + root + rel

    hipMemsetAsync(prevc,   0, (size_t)NL*BATCH*HID*4, stream);
    hipMemsetAsync(prevh16, 0, (size_t)NL*BATCH*HID*2, stream);
    hipMemsetAsync(bar,     0, 4096, stream);

    k_setup_w   <<<dim3(16384), dim3(256), 0, stream>>>(W_ih, W_hh, b_ih, b_hh, Wcat, bsum);
    k_setup_misc<<<dim3(2048),  dim3(256), 0, stream>>>(attn_wx, attn_wh, attn_wht, attn_v, awx, whd, whtd, av);
    k_xs16      <<<dim3(16384), dim3(256), 0, stream>>>(xs, xsf);
    k_xattn     <<<dim3(8, SEQ, NL), dim3(512), 0, stream>>>(xsf, awx, xattn);

    k_fill<<<dim3(32, TAPE), dim3(512), 0, stream>>>(xsf, Wcat, bsum, htape16, ctape, 0, h0all);
    k_fill<<<dim3(32, TAPE), dim3(512), 0, stream>>>(h0all, Wcat + (size_t)NG*1024, bsum + NG,
                                                     htape16, ctape, 1, nullptr);

    // Plain (non-cooperative) launch: 256 blocks x 98.8 KiB LDS = 1 block/CU,
    // grid == #CUs -> all blocks co-resident by construction; capture-safe.
    SArgs sa;
    sa.xsf = xsf; sa.xattn = xattn; sa.Wcat = Wcat; sa.bsum = bsum;
    sa.whd = whd; sa.whtd = whtd; sa.av = av;
    sa.htape16 = htape16; sa.ctape = ctape;
    sa.prevc = prevc; sa.prevh16 = prevh16;
    sa.h016 = h016; sa.slotstage = slotstage; sa.out = out;
    sa.bar = bar;
    k_scan<<<dim3(NBLK), dim3(256), 0, stream>>>(sa);
}